// Round 13
// baseline (382.428 us; speedup 1.0000x reference)
//
#include <hip/hip_runtime.h>
#include <math.h>

#define NB_   8
#define INCH  512
#define OUTCH 256
#define NHEAD 8
#define DHEAD 32

typedef __attribute__((ext_vector_type(8))) short short8v;
typedef __attribute__((ext_vector_type(4))) short short4v;
typedef __attribute__((ext_vector_type(4))) float f32x4;

__device__ inline short f2bf(float f) {
    unsigned u = __float_as_uint(f);
    unsigned r = u + 0x7FFFu + ((u >> 16) & 1u);
    return (short)(r >> 16);
}

// ---------------- pack fp32 weight [Co][Ci] -> bf16 packed-k layout ----------------
// packed pos within 32-k tile: (q = (k%16)/4, h = k/16, r = k%4) -> q*8 + h*4 + r
__global__ void pack_w(const float* __restrict__ W, short* __restrict__ Wp, int Co, int Ci) {
    const int idx = blockIdx.x * 256 + threadIdx.x;
    if (idx >= Co * Ci) return;
    const int m = idx / Ci, i = idx % Ci;
    const int kt = i >> 5, w32 = i & 31;
    const int h = w32 >> 4, q = (w32 & 15) >> 2, r = w32 & 3;
    Wp[m * Ci + kt * 32 + q * 8 + h * 4 + r] = f2bf(W[idx]);
}

// ---------------- bias matrix: Bm[h][qb][j] packed bf16 from rel_table ----------------
__global__ void bias_mat(const float* __restrict__ rel, short* __restrict__ Bm) {
    const int idx = blockIdx.x * 256 + threadIdx.x;   // 8*256*256
    const int h  = idx >> 16;
    const int qb = (idx >> 8) & 255;
    const int pp = idx & 255;
    const int kt = pp >> 5, w = pp & 31;
    const int q = w >> 3, hh = (w >> 2) & 1, r = w & 3;
    const int j = kt * 32 + hh * 16 + q * 4 + r;
    const int qy = qb >> 4, qx = qb & 15;
    const int ky = j >> 4, kx = j & 15;
    Bm[idx] = f2bf(rel[((qy - ky + 15) * 31 + (qx - kx + 15)) * NHEAD + h]);
}

// ---------------- pack v16 (conv layout) -> Xpv[h][(b*32+d)][j packed] bf16 ----------------
__global__ void pack_vT(const float* __restrict__ v16, short* __restrict__ Xpv) {
    const int h = blockIdx.x;
    const int b = blockIdx.y;
    const int tid = threadIdx.x;
#pragma unroll
    for (int cc = 0; cc < 4; ++cc) {
        const int c  = tid * 4 + cc;      // 0..1023
        const int d  = c >> 5;
        const int ck = c & 31;
        const int kt = ck >> 2, q = ck & 3;
        const float* vp = v16 + ((size_t)(b * 256 + d * NHEAD + h)) * 256;
        short8v v;
#pragma unroll
        for (int hh = 0; hh < 2; ++hh)
#pragma unroll
            for (int r = 0; r < 4; ++r)
                v[hh * 4 + r] = f2bf(vp[kt * 32 + hh * 16 + q * 4 + r]);
        *reinterpret_cast<short8v*>(&Xpv[(size_t)h * 65536 + (b * 32 + d) * 256 + kt * 32 + q * 8]) = v;
    }
}

// ---------------- LDS-staged pack: fp32 [B][C][P] -> packed bf16 [B][P][C] ----------------
template <int BN_RELU>
__global__ __launch_bounds__(256, 4)
void pack_tile(const float* __restrict__ in, const float* __restrict__ scale,
               const float* __restrict__ shift, short* __restrict__ outp, int C, int P) {
    __shared__ float s[32][256];
    const int tid = threadIdx.x;
    const int p0 = blockIdx.x * 256;
    const int kt = blockIdx.y;
    const int b  = blockIdx.z;
#pragma unroll
    for (int c = 0; c < 32; ++c) {
        const int gc = kt * 32 + c;
        float v = in[((size_t)b * C + gc) * P + p0 + tid];
        if (BN_RELU) {
            v = v * scale[gc] + shift[gc];
            v = v > 0.f ? v : 0.f;
        }
        s[c][tid] = v;
    }
    __syncthreads();
    short* op = outp + ((size_t)b * P + p0 + tid) * C + kt * 32;
#pragma unroll
    for (int q = 0; q < 4; ++q) {
        short8v v;
#pragma unroll
        for (int h = 0; h < 2; ++h)
#pragma unroll
            for (int r = 0; r < 4; ++r)
                v[h * 4 + r] = f2bf(s[h * 16 + q * 4 + r][tid]);
        *reinterpret_cast<short8v*>(op + q * 8) = v;
    }
}

// ---------------- direct (optional BN) + depthwise 3x3 -> packed bf16 ----------------
template <int W_>
__global__ __launch_bounds__(256, 4)
void dw3_direct(const float* __restrict__ in, const float* __restrict__ scale,
                const float* __restrict__ shift, const float* __restrict__ dw,
                short* __restrict__ outp, int C, int H) {
    constexpr int XG = W_ / 8;
    constexpr int RT = 256 / W_;
    __shared__ __align__(16) short so[256][40];
    const int tid = threadIdx.x;
    const int cg  = tid & 7;
    const int pxg = tid >> 3;
    const int row = pxg / XG;
    const int xg  = pxg % XG;
    const int x0  = xg * 8;
    const int y   = blockIdx.x * RT + row;
    const int kt  = blockIdx.y;
    const int b   = blockIdx.z;
    const int P   = H * W_;

    float acc[4][8];
#pragma unroll
    for (int r = 0; r < 4; ++r)
#pragma unroll
        for (int j = 0; j < 8; ++j) acc[r][j] = 0.f;

#pragma unroll
    for (int r = 0; r < 4; ++r) {
        const int gc = kt * 32 + cg * 4 + r;
        const float sc = scale ? scale[gc] : 1.f;
        const float sh = scale ? shift[gc] : 0.f;
        const float* wp = dw + gc * 9;
#pragma unroll
        for (int dy = 0; dy < 3; ++dy) {
            const int gy = y - 1 + dy;
            if (gy < 0 || gy >= H) continue;
            const float* bp = in + ((size_t)b * C + gc) * P + gy * W_;
            float w[10];
            w[0] = (x0 > 0) ? bp[x0 - 1] : 0.f;
            const float4 m0 = *reinterpret_cast<const float4*>(bp + x0);
            const float4 m1 = *reinterpret_cast<const float4*>(bp + x0 + 4);
            w[1] = m0.x; w[2] = m0.y; w[3] = m0.z; w[4] = m0.w;
            w[5] = m1.x; w[6] = m1.y; w[7] = m1.z; w[8] = m1.w;
            w[9] = (x0 + 8 < W_) ? bp[x0 + 8] : 0.f;
            if (scale) {
#pragma unroll
                for (int t = 0; t < 10; ++t) w[t] = w[t] * sc + sh;
                if (x0 == 0) w[0] = 0.f;
                if (x0 + 8 >= W_) w[9] = 0.f;
            }
            const float t0 = wp[dy * 3 + 0], t1 = wp[dy * 3 + 1], t2 = wp[dy * 3 + 2];
#pragma unroll
            for (int j = 0; j < 8; ++j)
                acc[r][j] += t0 * w[j] + t1 * w[j + 1] + t2 * w[j + 2];
        }
    }

    const int posb = (cg & 3) * 8 + (cg >> 2) * 4;
#pragma unroll
    for (int j = 0; j < 8; ++j) {
        short4v v;
#pragma unroll
        for (int r = 0; r < 4; ++r) v[r] = f2bf(acc[r][j]);
        *reinterpret_cast<short4v*>(&so[pxg * 8 + j][posb]) = v;
    }
    __syncthreads();
    short* op = outp + ((size_t)b * P + blockIdx.x * 256 + tid) * C + kt * 32;
#pragma unroll
    for (int q = 0; q < 4; ++q)
        *reinterpret_cast<short8v*>(op + q * 8) = *reinterpret_cast<const short8v*>(&so[tid][q * 8]);
}

// ---------------- MFMA bf16 GEMM: out[z,m,p] = sum_i W[m,i] X[z,i,p] ----------------
// BM=128, BN=64, BK=32; 4 waves (2x2), wave tile 64x32.
// Epilogue: LDS-staged C (stride 68) -> full-cacheline coalesced stores.
// RES_MODE: 0 none, 1 plain residual, 2 bilinear-upsampled residual from x1c [B][Co][32*32] (P==4096 only).
template <int RES_MODE, int BATCH_W>
__global__ __launch_bounds__(256, 4)
void mfma_pw(const short* __restrict__ Xp, const short* __restrict__ Wp,
             const float* __restrict__ bias, const float* __restrict__ res,
             float* __restrict__ out, int Ci, int Co, int P) {
    __shared__ __align__(16) char smem[64 * 68 * 4];   // 17408B: staging (12KB) then C-tile
    short* Ash = (short*)smem;            // 8KB [q4][m128][8]
    short* Bsh = (short*)(smem + 8192);   // 4KB [q4][n64][8]
    float* cs  = (float*)smem;            // 64 rows x 68 stride (reused after K loop)

    const int b   = blockIdx.z;
    const int m0  = blockIdx.y * 128;
    const int n0  = blockIdx.x * 64;
    const int tid = threadIdx.x;
    const int lane = tid & 63;
    const int wid  = tid >> 6;
    const int wr = wid >> 1, wc = wid & 1;
    const int ql = lane >> 4, l16 = lane & 15;

    f32x4 acc[4][2];
#pragma unroll
    for (int mb = 0; mb < 4; ++mb)
#pragma unroll
        for (int nb = 0; nb < 2; ++nb) acc[mb][nb] = (f32x4){0.f, 0.f, 0.f, 0.f};

    const int sm_ = tid & 127;  // A stage: m
    const int sq_ = tid >> 7;   // A stage: q sub
    const int bn_ = tid & 63;   // B stage: n
    const int bq_ = tid >> 6;   // B stage: q

    const size_t wrow = (size_t)(m0 + sm_) * Ci + (BATCH_W ? (size_t)b * Co * Ci : 0);
    const size_t xrow = ((size_t)b * P + n0 + bn_) * Ci;

    const int nkt = Ci >> 5;
    for (int kt = 0; kt < nkt; ++kt) {
        const int kof = kt * 32;
#pragma unroll
        for (int r = 0; r < 2; ++r) {
            const int q = r * 2 + sq_;
            __builtin_amdgcn_global_load_lds(Wp + wrow + kof + q * 8, &Ash[r * 2048 + tid * 8], 16, 0, 0);
        }
        __builtin_amdgcn_global_load_lds(Xp + xrow + kof + bq_ * 8, &Bsh[tid * 8], 16, 0, 0);
        __syncthreads();

        short8v a[4], bf[2];
#pragma unroll
        for (int mb = 0; mb < 4; ++mb)
            a[mb] = *reinterpret_cast<const short8v*>(&Ash[ql * 1024 + (wr * 64 + mb * 16 + l16) * 8]);
#pragma unroll
        for (int nb = 0; nb < 2; ++nb)
            bf[nb] = *reinterpret_cast<const short8v*>(&Bsh[ql * 512 + (wc * 32 + nb * 16 + l16) * 8]);
#pragma unroll
        for (int mb = 0; mb < 4; ++mb)
#pragma unroll
            for (int nb = 0; nb < 2; ++nb)
                acc[mb][nb] = __builtin_amdgcn_mfma_f32_16x16x32_bf16(a[mb], bf[nb], acc[mb][nb], 0, 0, 0);
        __syncthreads();
    }

    // bilinear y-params (block-uniform when P==4096: block covers one image row)
    int ry0 = 0, ry1 = 0; float rwy = 0.f;
    if (RES_MODE == 2) {
        const int yy = n0 >> 6;
        const float fy = (float)yy * (31.f / 63.f);
        ry0 = (int)fy; ry1 = min(ry0 + 1, 31); rwy = fy - (float)ry0;
    }

    // epilogue: two 64-row chunks through LDS, coalesced full-line stores
#pragma unroll
    for (int chunk = 0; chunk < 2; ++chunk) {
        __syncthreads();
#pragma unroll
        for (int mbh = 0; mbh < 2; ++mbh) {
            const int mb = chunk * 2 + mbh;
            const int lr0 = wr * 32 + mbh * 16 + ql * 4;
#pragma unroll
            for (int nb = 0; nb < 2; ++nb) {
                const int lc = wc * 32 + nb * 16 + l16;
#pragma unroll
                for (int j = 0; j < 4; ++j)
                    cs[(lr0 + j) * 68 + lc] = acc[mb][nb][j];
            }
        }
        __syncthreads();

        const int lr  = tid >> 2;            // 0..63
        const int c0  = (tid & 3) * 16;      // 0,16,32,48
        const int wr2 = lr >> 5, rem = lr & 31;
        const int grow = m0 + wr2 * 64 + chunk * 32 + rem;
        const size_t obase = ((size_t)b * Co + grow) * P + n0 + c0;
        const float bv = bias ? bias[grow] : 0.f;

        const float* pl = (RES_MODE == 2) ? res + ((size_t)b * Co + grow) * 1024 : nullptr;

#pragma unroll
        for (int k = 0; k < 4; ++k) {
            float4 v = *reinterpret_cast<const float4*>(&cs[lr * 68 + c0 + k * 4]);
            v.x += bv; v.y += bv; v.z += bv; v.w += bv;
            if (RES_MODE == 1) {
                const float4 rv = *reinterpret_cast<const float4*>(res + obase + k * 4);
                v.x += rv.x; v.y += rv.y; v.z += rv.z; v.w += rv.w;
            }
            if (RES_MODE == 2) {
                float* ve = &v.x;
#pragma unroll
                for (int e = 0; e < 4; ++e) {
                    const int xx = c0 + k * 4 + e;
                    const float fx = (float)xx * (31.f / 63.f);
                    const int rx0 = (int)fx;
                    const int rx1 = min(rx0 + 1, 31);
                    const float rwx = fx - (float)rx0;
                    const float r0 = pl[ry0 * 32 + rx0] * (1.f - rwx) + pl[ry0 * 32 + rx1] * rwx;
                    const float r1 = pl[ry1 * 32 + rx0] * (1.f - rwx) + pl[ry1 * 32 + rx1] * rwx;
                    ve[e] += r0 * (1.f - rwy) + r1 * rwy;
                }
            }
            *reinterpret_cast<float4*>(out + obase + k * 4) = v;
        }
    }
}

// ---------------- bilinear resize (compile-time dims; all pow2) ----------------
template <int C, int Hi, int Wi, int Ho, int Wo>
__global__ void resize_bilinear(const float* __restrict__ in, float* __restrict__ out, int ibs) {
    const int idx = blockIdx.x * 256 + threadIdx.x;
    const int x = idx & (Wo - 1);
    const int y = (idx / Wo) & (Ho - 1);
    const int c = (idx / (Wo * Ho)) & (C - 1);
    const int b = idx / (Wo * Ho * C);
    const float fy = (float)y * (float)(Hi - 1) / (float)(Ho - 1);
    const float fx = (float)x * (float)(Wi - 1) / (float)(Wo - 1);
    int y0 = (int)floorf(fy); int y1 = min(y0 + 1, Hi - 1); const float wy = fy - (float)y0;
    int x0 = (int)floorf(fx); int x1 = min(x0 + 1, Wi - 1); const float wx = fx - (float)x0;
    const float* pc = in + (size_t)b * ibs + (size_t)c * Hi * Wi;
    const float r0 = pc[y0 * Wi + x0] * (1.f - wx) + pc[y0 * Wi + x1] * wx;
    const float r1 = pc[y1 * Wi + x0] * (1.f - wx) + pc[y1 * Wi + x1] * wx;
    out[idx] = r0 * (1.f - wy) + r1 * wy;
}

// ---------------- BN stats, two-phase ----------------
__global__ __launch_bounds__(256, 8)
void bn_stats_part(const float* __restrict__ in, float* __restrict__ part, int C, int HW) {
    const int b = blockIdx.x;
    const int c = blockIdx.y;
    const float* p = in + ((size_t)b * C + c) * HW;
    float s1 = 0.f, s2 = 0.f;
    for (int i = threadIdx.x * 4; i < HW; i += 1024) {
        const float4 v = *reinterpret_cast<const float4*>(p + i);
        s1 += v.x + v.y + v.z + v.w;
        s2 += v.x * v.x + v.y * v.y + v.z * v.z + v.w * v.w;
    }
#pragma unroll
    for (int o = 32; o >= 1; o >>= 1) {
        s1 += __shfl_xor(s1, o);
        s2 += __shfl_xor(s2, o);
    }
    __shared__ float sh1[4], sh2[4];
    if ((threadIdx.x & 63) == 0) { sh1[threadIdx.x >> 6] = s1; sh2[threadIdx.x >> 6] = s2; }
    __syncthreads();
    if (threadIdx.x == 0) {
        part[((size_t)c * gridDim.x + b) * 2 + 0] = sh1[0] + sh1[1] + sh1[2] + sh1[3];
        part[((size_t)c * gridDim.x + b) * 2 + 1] = sh2[0] + sh2[1] + sh2[2] + sh2[3];
    }
}

__global__ void bn_finish(const float* __restrict__ part, const float* __restrict__ g,
                          const float* __restrict__ bt, float* __restrict__ scale,
                          float* __restrict__ shift, int C, int HW, float eps) {
    const int c = blockIdx.x * 256 + threadIdx.x;
    if (c >= C) return;
    float s1 = 0.f, s2 = 0.f;
#pragma unroll
    for (int b = 0; b < NB_; ++b) {
        s1 += part[((size_t)c * NB_ + b) * 2 + 0];
        s2 += part[((size_t)c * NB_ + b) * 2 + 1];
    }
    const float invN = 1.f / (float)(NB_ * HW);
    const float m = s1 * invN;
    const float var = s2 * invN - m * m;
    const float sc = g[c] * rsqrtf(var + eps);
    scale[c] = sc;
    shift[c] = bt[c] - m * sc;
}

// ---------------- LN (optional) + split heads ----------------
__global__ void ln_split(const float* __restrict__ in, const float* __restrict__ g,
                         const float* __restrict__ bt, float* __restrict__ out,
                         int HW, int applyLN, float eps) {
    const int row = blockIdx.x * 8 + (threadIdx.x >> 5);
    const int d = threadIdx.x & 31;
    const int j = row % HW;
    const int h = (row / HW) % NHEAD;
    const int b = row / (HW * NHEAD);
    float v = in[((size_t)b * OUTCH + d * NHEAD + h) * HW + j];
    if (applyLN) {
        float s1 = v, s2 = v * v;
#pragma unroll
        for (int o = 16; o >= 1; o >>= 1) {
            s1 += __shfl_xor(s1, o, 32);
            s2 += __shfl_xor(s2, o, 32);
        }
        const float m = s1 * (1.f / 32.f);
        const float var = s2 * (1.f / 32.f) - m * m;
        v = (v - m) * rsqrtf(var + eps) * g[h * 32 + d] + bt[h * 32 + d];
    }
    out[((size_t)(b * NHEAD + h) * HW + j) * 32 + d] = v;
}

// ---------------- M = k^T v ----------------
__global__ void kv_outer(const float* __restrict__ kn, const float* __restrict__ vh,
                         float* __restrict__ M) {
    __shared__ float vs[256][32];
    const int bh = blockIdx.x;
    const float* kp = kn + (size_t)bh * 256 * 32;
    const float* vp = vh + (size_t)bh * 256 * 32;
    const int tid = threadIdx.y * 32 + threadIdx.x;
    for (int t = tid; t < 256 * 32; t += 1024) vs[t >> 5][t & 31] = vp[t];
    __syncthreads();
    const int e = threadIdx.x, dd = threadIdx.y;
    float acc = 0.f;
    for (int j = 0; j < 256; ++j) acc += kp[j * 32 + e] * vs[j][dd];
    M[((size_t)bh * 32 + e) * 32 + dd] = acc;
}

// ---------------- attention out: o = (LN(q) @ M + Bv)/32, 2 px/thread, SGPR-M ----------------
// Bv2 layout: [h][qb][b*32+d]
__global__ __launch_bounds__(256, 2)
void attn_out(const float* __restrict__ q, const float* __restrict__ gq,
              const float* __restrict__ bq, const float* __restrict__ M,
              const float* __restrict__ Bv, float* __restrict__ o) {
    const int gid = blockIdx.x * 256 + threadIdx.x;
    const int ip = (gid & 2047) * 2;
    const int h  = (gid >> 11) & 7;
    const int b  = gid >> 14;

    const float* Mp = M + ((size_t)(b * NHEAD + h) << 10);
    {
        uint64_t a = (uint64_t)Mp;
        uint32_t lo = __builtin_amdgcn_readfirstlane((uint32_t)a);
        uint32_t hi = __builtin_amdgcn_readfirstlane((uint32_t)(a >> 32));
        Mp = (const float*)((((uint64_t)hi) << 32) | lo);
    }

    const float* qp = q + (size_t)b * OUTCH * 4096 + h * 4096 + ip;
    float q0[32], q1[32];
    float a1 = 0.f, a2 = 0.f, b1 = 0.f, b2 = 0.f;
#pragma unroll
    for (int d = 0; d < 32; ++d) {
        const float2 v = *reinterpret_cast<const float2*>(qp + (size_t)d * NHEAD * 4096);
        q0[d] = v.x; q1[d] = v.y;
        a1 += v.x; a2 += v.x * v.x;
        b1 += v.y; b2 += v.y * v.y;
    }
    {
        const float m0 = a1 * (1.f / 32.f);
        const float r0 = rsqrtf(a2 * (1.f / 32.f) - m0 * m0 + 1e-6f);
        const float m1 = b1 * (1.f / 32.f);
        const float r1 = rsqrtf(b2 * (1.f / 32.f) - m1 * m1 + 1e-6f);
#pragma unroll
        for (int d = 0; d < 32; ++d) {
            const float gg = gq[h * 32 + d], bb = bq[h * 32 + d];
            q0[d] = (q0[d] - m0) * r0 * gg + bb;
            q1[d] = (q1[d] - m1) * r1 * gg + bb;
        }
    }

    const int y = ip >> 6, x = ip & 63;
    const int qb0 = (y >> 2) * 16 + (x >> 2);
    const int qb1 = (y >> 2) * 16 + ((x + 1) >> 2);
    const float* Bp0 = Bv + ((size_t)h * 256 + qb0) * 256 + b * 32;
    const float* Bp1 = Bv + ((size_t)h * 256 + qb1) * 256 + b * 32;
    float acc0[32], acc1[32];
#pragma unroll
    for (int t = 0; t < 8; ++t) {
        const float4 v0 = *reinterpret_cast<const float4*>(Bp0 + t * 4);
        const float4 v1 = *reinterpret_cast<const float4*>(Bp1 + t * 4);
        acc0[t * 4 + 0] = v0.x; acc0[t * 4 + 1] = v0.y; acc0[t * 4 + 2] = v0.z; acc0[t * 4 + 3] = v0.w;
        acc1[t * 4 + 0] = v1.x; acc1[t * 4 + 1] = v1.y; acc1[t * 4 + 2] = v1.z; acc1[t * 4 + 3] = v1.w;
    }

    for (int e = 0; e < 32; ++e) {
        const float qe0 = q0[e], qe1 = q1[e];
#pragma unroll
        for (int d = 0; d < 32; ++d) {
            const float m = Mp[e * 32 + d];
            acc0[d] += qe0 * m;
            acc1[d] += qe1 * m;
        }
    }

    float* op = o + (size_t)b * OUTCH * 4096 + h * 4096 + ip;
#pragma unroll
    for (int d = 0; d < 32; ++d) {
        float2 v;
        v.x = acc0[d] * (1.f / 32.f);
        v.y = acc1[d] * (1.f / 32.f);
        *reinterpret_cast<float2*>(op + (size_t)d * NHEAD * 4096) = v;
    }
}

extern "C" void kernel_launch(void* const* d_in, const int* in_sizes, int n_in,
                              void* d_out, int out_size, void* d_ws, size_t ws_size,
                              hipStream_t stream) {
    const float* x1        = (const float*)d_in[0];
    const float* x2        = (const float*)d_in[1];
    const float* conv_ch_w = (const float*)d_in[2];
    const float* conv_ch_b = (const float*)d_in[3];
    const float* norm_l_g  = (const float*)d_in[4];
    const float* norm_l_b  = (const float*)d_in[5];
    const float* norm_h_g  = (const float*)d_in[6];
    const float* norm_h_b  = (const float*)d_in[7];
    const float* to_kv_dw  = (const float*)d_in[8];
    const float* to_kv_pw  = (const float*)d_in[9];
    const float* to_q_dw   = (const float*)d_in[10];
    const float* to_q_pw   = (const float*)d_in[11];
    const float* to_out_dw = (const float*)d_in[12];
    const float* to_out_pw = (const float*)d_in[13];
    const float* rel_table = (const float*)d_in[14];
    const float* normq_g   = (const float*)d_in[15];
    const float* normq_b   = (const float*)d_in[16];
    const float* normk_g   = (const float*)d_in[17];
    const float* normk_b   = (const float*)d_in[18];
    const float* norm2_g   = (const float*)d_in[19];
    const float* norm2_b   = (const float*)d_in[20];
    const float* mlp_w     = (const float*)d_in[21];
    float* Dout = (float*)d_out;

    float* ws = (float*)d_ws;
    const size_t NBIG = (size_t)NB_ * OUTCH * 4096;  // 8388608 floats (32 MB)
    float* X1C = ws;               // x1c kept alive: [8][256][1024] = 8 MB
    float* A   = ws + NBIG;
    float* Bb  = ws + 2 * NBIG;
    float* sm  = ws + 3 * NBIG;
    float* scale1 = sm;            float* shift1 = sm + 512;
    float* scale2 = sm + 1024;     float* shift2 = sm + 1280;
    float* scale3 = sm + 1536;     float* shift3 = sm + 1792;
    float* k16 = sm + 2048;
    float* v16 = k16 + 524288;
    float* kn  = v16 + 524288;
    float* vh  = kn  + 524288;
    float* Mm  = vh  + 524288;
    float* Bv  = Mm  + 65536;      // Bv2: [h][qb][b*32+d], 524288 floats
    short* Wq  = (short*)(Bv + 524288);
    short* Wo  = Wq + 65536;
    short* Wm  = Wo + 65536;
    short* Wc  = Wm + 65536;       // conv_ch_w packed: 256x512
    short* Wkv = Wc + 131072;      // to_kv_pw packed: 512x512
    float* bnpart = (float*)(Wkv + 262144);  // 8192 floats max

    short* Xp1 = (short*)Bb;             // x1 packed: 8 MB
    short* Xp2 = (short*)Bb + 4194304;   // kv_dw packed: 8 MB
    short* Xp  = (short*)Bb;             // big packed X (16 MB), steps 8+
    short* Bmp = (short*)Bb + 8388608;   // bias matrices: 1 MB
    short* Xpv = Bmp + 524288;           // packed v^T: 1 MB
    float* kv  = A;                      // 16 MB fp32 [8,512,1024]

    // 0. pack weights + bias matrix
    pack_w<<<256, 256, 0, stream>>>(to_q_pw, Wq, 256, 256);
    pack_w<<<256, 256, 0, stream>>>(to_out_pw, Wo, 256, 256);
    pack_w<<<256, 256, 0, stream>>>(mlp_w, Wm, 256, 256);
    pack_w<<<512, 256, 0, stream>>>(conv_ch_w, Wc, 256, 512);
    pack_w<<<1024, 256, 0, stream>>>(to_kv_pw, Wkv, 512, 512);
    bias_mat<<<2048, 256, 0, stream>>>(rel_table, Bmp);

    // 1. x1 -> packed bf16; x1c = mfma(x1p, Wc) + bias -> X1C (kept alive)
    pack_tile<0><<<dim3(4, 16, 8), 256, 0, stream>>>(x1, nullptr, nullptr, Xp1, 512, 1024);
    mfma_pw<0, 0><<<dim3(16, 2, 8), 256, 0, stream>>>(Xp1, Wc, conv_ch_b, nullptr, X1C, 512, 256, 1024);
    // 3. BN stats x1 (two-phase)
    bn_stats_part<<<dim3(8, 512), 256, 0, stream>>>(x1, bnpart, 512, 1024);
    bn_finish<<<2, 256, 0, stream>>>(bnpart, norm_l_g, norm_l_b, scale1, shift1, 512, 1024, 1e-5f);
    // 4. kv_dw = dw3(BN(x1)) -> Xp2 (packed bf16)
    dw3_direct<32><<<dim3(4, 16, 8), 256, 0, stream>>>(x1, scale1, shift1, to_kv_dw, Xp2, 512, 32);
    // 5. kv = mfma(Xp2, Wkv) -> A
    mfma_pw<0, 0><<<dim3(16, 4, 8), 256, 0, stream>>>(Xp2, Wkv, nullptr, nullptr, kv, 512, 512, 1024);
    // 6. k16, v16 = resize to 16x16
    resize_bilinear<256, 32, 32, 16, 16><<<2048, 256, 0, stream>>>(kv, k16, 512 * 1024);
    resize_bilinear<256, 32, 32, 16, 16><<<2048, 256, 0, stream>>>(kv + 256 * 1024, v16, 512 * 1024);
    // 7. BN stats x2 (two-phase)
    bn_stats_part<<<dim3(8, 256), 256, 0, stream>>>(x2, bnpart, 256, 4096);
    bn_finish<<<1, 256, 0, stream>>>(bnpart, norm_h_g, norm_h_b, scale2, shift2, 256, 4096, 1e-5f);
    // 8. q_dw = dw3(BN(x2)) -> Xp (packed bf16)
    dw3_direct<64><<<dim3(16, 8, 8), 256, 0, stream>>>(x2, scale2, shift2, to_q_dw, Xp, 256, 64);
    // 9. q = mfma(Xp, Wq) -> A
    mfma_pw<0, 0><<<dim3(64, 2, 8), 256, 0, stream>>>(Xp, Wq, nullptr, nullptr, A, 256, 256, 4096);
    // 10. kn = LN(split(k16)); vh = split(v16); Xpv = packed v^T
    ln_split<<<2048, 256, 0, stream>>>(k16, normk_g, normk_b, kn, 256, 1, 1e-6f);
    ln_split<<<2048, 256, 0, stream>>>(v16, nullptr, nullptr, vh, 256, 0, 0.f);
    pack_vT<<<dim3(8, 8), 256, 0, stream>>>(v16, Xpv);
    // 11. M = k^T v
    kv_outer<<<64, dim3(32, 32), 0, stream>>>(kn, vh, Mm);
    // 12. Bv2[h][qb][b*32+d] = bias_h @ V_h  (batched MFMA GEMM)
    mfma_pw<0, 1><<<dim3(4, 2, 8), 256, 0, stream>>>(Xpv, Bmp, nullptr, nullptr, Bv, 256, 256, 256);
    // 13. o = (LN(q) @ M + Bv)/32, in-place on A
    attn_out<<<512, 256, 0, stream>>>(A, normq_g, normq_b, Mm, Bv, A);
    // 14. out_dw = dw3(o) -> Xp (packed bf16)
    dw3_direct<64><<<dim3(16, 8, 8), 256, 0, stream>>>(A, nullptr, nullptr, to_out_dw, Xp, 256, 64);
    // 15. o2 = mfma(Xp, Wo) + bilinear(X1C) -> A  (res2; residue fused in coalesced epilogue)
    mfma_pw<2, 0><<<dim3(64, 2, 8), 256, 0, stream>>>(Xp, Wo, nullptr, X1C, A, 256, 256, 4096);
    // 16. BN stats o2 (two-phase)
    bn_stats_part<<<dim3(8, 256), 256, 0, stream>>>(A, bnpart, 256, 4096);
    bn_finish<<<1, 256, 0, stream>>>(bnpart, norm2_g, norm2_b, scale3, shift3, 256, 4096, 1e-5f);
    // 17. r = relu(BN(o2)) -> Xp (packed bf16)
    pack_tile<1><<<dim3(16, 8, 8), 256, 0, stream>>>(A, scale3, shift3, Xp, 256, 4096);
    // 18. out = mfma(Xp, Wm) + res2(A) -> d_out
    mfma_pw<1, 0><<<dim3(64, 2, 8), 256, 0, stream>>>(Xp, Wm, nullptr, A, Dout, 256, 256, 4096);
}

// Round 14
// 302.747 us; speedup vs baseline: 1.2632x; 1.2632x over previous
//
#include <hip/hip_runtime.h>
#include <math.h>

#define NB_   8
#define INCH  512
#define OUTCH 256
#define NHEAD 8
#define DHEAD 32

typedef __attribute__((ext_vector_type(8))) short short8v;
typedef __attribute__((ext_vector_type(4))) short short4v;
typedef __attribute__((ext_vector_type(4))) float f32x4;

__device__ inline short f2bf(float f) {
    unsigned u = __float_as_uint(f);
    unsigned r = u + 0x7FFFu + ((u >> 16) & 1u);
    return (short)(r >> 16);
}

// ---------------- pack fp32 weight [Co][Ci] -> bf16 packed-k layout ----------------
// packed pos within 32-k tile: (q = (k%16)/4, h = k/16, r = k%4) -> q*8 + h*4 + r
__global__ void pack_w(const float* __restrict__ W, short* __restrict__ Wp, int Co, int Ci) {
    const int idx = blockIdx.x * 256 + threadIdx.x;
    if (idx >= Co * Ci) return;
    const int m = idx / Ci, i = idx % Ci;
    const int kt = i >> 5, w32 = i & 31;
    const int h = w32 >> 4, q = (w32 & 15) >> 2, r = w32 & 3;
    Wp[m * Ci + kt * 32 + q * 8 + h * 4 + r] = f2bf(W[idx]);
}

// ---------------- bias matrix: Bm[h][qb][j] packed bf16 from rel_table ----------------
__global__ void bias_mat(const float* __restrict__ rel, short* __restrict__ Bm) {
    const int idx = blockIdx.x * 256 + threadIdx.x;   // 8*256*256
    const int h  = idx >> 16;
    const int qb = (idx >> 8) & 255;
    const int pp = idx & 255;
    const int kt = pp >> 5, w = pp & 31;
    const int q = w >> 3, hh = (w >> 2) & 1, r = w & 3;
    const int j = kt * 32 + hh * 16 + q * 4 + r;
    const int qy = qb >> 4, qx = qb & 15;
    const int ky = j >> 4, kx = j & 15;
    Bm[idx] = f2bf(rel[((qy - ky + 15) * 31 + (qx - kx + 15)) * NHEAD + h]);
}

// ---------------- pack v16 (conv layout) -> Xpv[h][(b*32+d)][j packed] bf16 ----------------
__global__ void pack_vT(const float* __restrict__ v16, short* __restrict__ Xpv) {
    const int h = blockIdx.x;
    const int b = blockIdx.y;
    const int tid = threadIdx.x;
#pragma unroll
    for (int cc = 0; cc < 4; ++cc) {
        const int c  = tid * 4 + cc;      // 0..1023
        const int d  = c >> 5;
        const int ck = c & 31;
        const int kt = ck >> 2, q = ck & 3;
        const float* vp = v16 + ((size_t)(b * 256 + d * NHEAD + h)) * 256;
        short8v v;
#pragma unroll
        for (int hh = 0; hh < 2; ++hh)
#pragma unroll
            for (int r = 0; r < 4; ++r)
                v[hh * 4 + r] = f2bf(vp[kt * 32 + hh * 16 + q * 4 + r]);
        *reinterpret_cast<short8v*>(&Xpv[(size_t)h * 65536 + (b * 32 + d) * 256 + kt * 32 + q * 8]) = v;
    }
}

// ---------------- LDS-staged pack: fp32 [B][C][P] -> packed bf16 [B][P][C] ----------------
template <int BN_RELU>
__global__ __launch_bounds__(256, 4)
void pack_tile(const float* __restrict__ in, const float* __restrict__ scale,
               const float* __restrict__ shift, short* __restrict__ outp, int C, int P) {
    __shared__ float s[32][256];
    const int tid = threadIdx.x;
    const int p0 = blockIdx.x * 256;
    const int kt = blockIdx.y;
    const int b  = blockIdx.z;
#pragma unroll
    for (int c = 0; c < 32; ++c) {
        const int gc = kt * 32 + c;
        float v = in[((size_t)b * C + gc) * P + p0 + tid];
        if (BN_RELU) {
            v = v * scale[gc] + shift[gc];
            v = v > 0.f ? v : 0.f;
        }
        s[c][tid] = v;
    }
    __syncthreads();
    short* op = outp + ((size_t)b * P + p0 + tid) * C + kt * 32;
#pragma unroll
    for (int q = 0; q < 4; ++q) {
        short8v v;
#pragma unroll
        for (int h = 0; h < 2; ++h)
#pragma unroll
            for (int r = 0; r < 4; ++r)
                v[h * 4 + r] = f2bf(s[h * 16 + q * 4 + r][tid]);
        *reinterpret_cast<short8v*>(op + q * 8) = v;
    }
}

// ---------------- direct (optional BN) + depthwise 3x3 -> packed bf16 ----------------
template <int W_>
__global__ __launch_bounds__(256, 4)
void dw3_direct(const float* __restrict__ in, const float* __restrict__ scale,
                const float* __restrict__ shift, const float* __restrict__ dw,
                short* __restrict__ outp, int C, int H) {
    constexpr int XG = W_ / 8;
    constexpr int RT = 256 / W_;
    __shared__ __align__(16) short so[256][40];
    const int tid = threadIdx.x;
    const int cg  = tid & 7;
    const int pxg = tid >> 3;
    const int row = pxg / XG;
    const int xg  = pxg % XG;
    const int x0  = xg * 8;
    const int y   = blockIdx.x * RT + row;
    const int kt  = blockIdx.y;
    const int b   = blockIdx.z;
    const int P   = H * W_;

    float acc[4][8];
#pragma unroll
    for (int r = 0; r < 4; ++r)
#pragma unroll
        for (int j = 0; j < 8; ++j) acc[r][j] = 0.f;

#pragma unroll
    for (int r = 0; r < 4; ++r) {
        const int gc = kt * 32 + cg * 4 + r;
        const float sc = scale ? scale[gc] : 1.f;
        const float sh = scale ? shift[gc] : 0.f;
        const float* wp = dw + gc * 9;
#pragma unroll
        for (int dy = 0; dy < 3; ++dy) {
            const int gy = y - 1 + dy;
            if (gy < 0 || gy >= H) continue;
            const float* bp = in + ((size_t)b * C + gc) * P + gy * W_;
            float w[10];
            w[0] = (x0 > 0) ? bp[x0 - 1] : 0.f;
            const float4 m0 = *reinterpret_cast<const float4*>(bp + x0);
            const float4 m1 = *reinterpret_cast<const float4*>(bp + x0 + 4);
            w[1] = m0.x; w[2] = m0.y; w[3] = m0.z; w[4] = m0.w;
            w[5] = m1.x; w[6] = m1.y; w[7] = m1.z; w[8] = m1.w;
            w[9] = (x0 + 8 < W_) ? bp[x0 + 8] : 0.f;
            if (scale) {
#pragma unroll
                for (int t = 0; t < 10; ++t) w[t] = w[t] * sc + sh;
                if (x0 == 0) w[0] = 0.f;
                if (x0 + 8 >= W_) w[9] = 0.f;
            }
            const float t0 = wp[dy * 3 + 0], t1 = wp[dy * 3 + 1], t2 = wp[dy * 3 + 2];
#pragma unroll
            for (int j = 0; j < 8; ++j)
                acc[r][j] += t0 * w[j] + t1 * w[j + 1] + t2 * w[j + 2];
        }
    }

    const int posb = (cg & 3) * 8 + (cg >> 2) * 4;
#pragma unroll
    for (int j = 0; j < 8; ++j) {
        short4v v;
#pragma unroll
        for (int r = 0; r < 4; ++r) v[r] = f2bf(acc[r][j]);
        *reinterpret_cast<short4v*>(&so[pxg * 8 + j][posb]) = v;
    }
    __syncthreads();
    short* op = outp + ((size_t)b * P + blockIdx.x * 256 + tid) * C + kt * 32;
#pragma unroll
    for (int q = 0; q < 4; ++q)
        *reinterpret_cast<short8v*>(op + q * 8) = *reinterpret_cast<const short8v*>(&so[tid][q * 8]);
}

// ---------------- MFMA bf16 GEMM: out[z,m,p] = sum_i W[m,i] X[z,i,p] ----------------
// BM=128, BN=64, BK=32; 4 waves (2x2), wave tile 64x32 (round-9/11 verified geometry).
// RES_MODE: 0 none, 1 plain residual, 2 bilinear-upsampled residual from x1c [B][Co][32*32].
template <int RES_MODE, int BATCH_W>
__global__ __launch_bounds__(256, 4)
void mfma_pw(const short* __restrict__ Xp, const short* __restrict__ Wp,
             const float* __restrict__ bias, const float* __restrict__ res,
             float* __restrict__ out, int Ci, int Co, int P) {
    __shared__ short Ash[4096];  // [q4][m128][8] = 8KB
    __shared__ short Bsh[2048];  // [q4][n64][8]  = 4KB
    const int b   = blockIdx.z;
    const int m0  = blockIdx.y * 128;
    const int n0  = blockIdx.x * 64;
    const int tid = threadIdx.x;
    const int lane = tid & 63;
    const int wid  = tid >> 6;
    const int wr = wid >> 1, wc = wid & 1;
    const int ql = lane >> 4, l16 = lane & 15;

    f32x4 acc[4][2];
#pragma unroll
    for (int mb = 0; mb < 4; ++mb)
#pragma unroll
        for (int nb = 0; nb < 2; ++nb) acc[mb][nb] = (f32x4){0.f, 0.f, 0.f, 0.f};

    const int sm_ = tid & 127;  // A stage: m
    const int sq_ = tid >> 7;   // A stage: q sub
    const int bn_ = tid & 63;   // B stage: n
    const int bq_ = tid >> 6;   // B stage: q

    const size_t wrow = (size_t)(m0 + sm_) * Ci + (BATCH_W ? (size_t)b * Co * Ci : 0);
    const size_t xrow = ((size_t)b * P + n0 + bn_) * Ci;

    const int nkt = Ci >> 5;
    for (int kt = 0; kt < nkt; ++kt) {
        const int kof = kt * 32;
#pragma unroll
        for (int r = 0; r < 2; ++r) {
            const int q = r * 2 + sq_;
            __builtin_amdgcn_global_load_lds(Wp + wrow + kof + q * 8, &Ash[r * 2048 + tid * 8], 16, 0, 0);
        }
        __builtin_amdgcn_global_load_lds(Xp + xrow + kof + bq_ * 8, &Bsh[tid * 8], 16, 0, 0);
        __syncthreads();

        short8v a[4], bf[2];
#pragma unroll
        for (int mb = 0; mb < 4; ++mb)
            a[mb] = *reinterpret_cast<const short8v*>(&Ash[ql * 1024 + (wr * 64 + mb * 16 + l16) * 8]);
#pragma unroll
        for (int nb = 0; nb < 2; ++nb)
            bf[nb] = *reinterpret_cast<const short8v*>(&Bsh[ql * 512 + (wc * 32 + nb * 16 + l16) * 8]);
#pragma unroll
        for (int mb = 0; mb < 4; ++mb)
#pragma unroll
            for (int nb = 0; nb < 2; ++nb)
                acc[mb][nb] = __builtin_amdgcn_mfma_f32_16x16x32_bf16(a[mb], bf[nb], acc[mb][nb], 0, 0, 0);
        __syncthreads();
    }

#pragma unroll
    for (int mb = 0; mb < 4; ++mb) {
        const int row = m0 + wr * 64 + mb * 16 + ql * 4;
#pragma unroll
        for (int nb = 0; nb < 2; ++nb) {
            const int col = n0 + wc * 32 + nb * 16 + l16;
            const size_t base = ((size_t)b * Co + row) * P + col;
            // bilinear params for RES_MODE==2 (out 64x64 from 32x32, linspace endpoints)
            int ry0 = 0, ry1 = 0, rx0 = 0, rx1 = 0; float rwy = 0.f, rwx = 0.f;
            if (RES_MODE == 2) {
                const int yy = col >> 6, xx = col & 63;
                const float fy = (float)yy * (31.f / 63.f);
                const float fx = (float)xx * (31.f / 63.f);
                ry0 = (int)fy; ry1 = min(ry0 + 1, 31); rwy = fy - (float)ry0;
                rx0 = (int)fx; rx1 = min(rx0 + 1, 31); rwx = fx - (float)rx0;
            }
#pragma unroll
            for (int j = 0; j < 4; ++j) {
                float v = acc[mb][nb][j];
                if (bias) v += bias[row + j];
                if (RES_MODE == 1) v += res[base + (size_t)j * P];
                if (RES_MODE == 2) {
                    const float* pl = res + ((size_t)b * Co + row + j) * 1024;
                    const float r0 = pl[ry0 * 32 + rx0] * (1.f - rwx) + pl[ry0 * 32 + rx1] * rwx;
                    const float r1 = pl[ry1 * 32 + rx0] * (1.f - rwx) + pl[ry1 * 32 + rx1] * rwx;
                    v += r0 * (1.f - rwy) + r1 * rwy;
                }
                out[base + (size_t)j * P] = v;
            }
        }
    }
}

// ---------------- bilinear resize (compile-time dims; all pow2) ----------------
template <int C, int Hi, int Wi, int Ho, int Wo>
__global__ void resize_bilinear(const float* __restrict__ in, float* __restrict__ out, int ibs) {
    const int idx = blockIdx.x * 256 + threadIdx.x;
    const int x = idx & (Wo - 1);
    const int y = (idx / Wo) & (Ho - 1);
    const int c = (idx / (Wo * Ho)) & (C - 1);
    const int b = idx / (Wo * Ho * C);
    const float fy = (float)y * (float)(Hi - 1) / (float)(Ho - 1);
    const float fx = (float)x * (float)(Wi - 1) / (float)(Wo - 1);
    int y0 = (int)floorf(fy); int y1 = min(y0 + 1, Hi - 1); const float wy = fy - (float)y0;
    int x0 = (int)floorf(fx); int x1 = min(x0 + 1, Wi - 1); const float wx = fx - (float)x0;
    const float* pc = in + (size_t)b * ibs + (size_t)c * Hi * Wi;
    const float r0 = pc[y0 * Wi + x0] * (1.f - wx) + pc[y0 * Wi + x1] * wx;
    const float r1 = pc[y1 * Wi + x0] * (1.f - wx) + pc[y1 * Wi + x1] * wx;
    out[idx] = r0 * (1.f - wy) + r1 * wy;
}

// ---------------- BN stats, two-phase ----------------
__global__ __launch_bounds__(256, 8)
void bn_stats_part(const float* __restrict__ in, float* __restrict__ part, int C, int HW) {
    const int b = blockIdx.x;
    const int c = blockIdx.y;
    const float* p = in + ((size_t)b * C + c) * HW;
    float s1 = 0.f, s2 = 0.f;
    for (int i = threadIdx.x * 4; i < HW; i += 1024) {
        const float4 v = *reinterpret_cast<const float4*>(p + i);
        s1 += v.x + v.y + v.z + v.w;
        s2 += v.x * v.x + v.y * v.y + v.z * v.z + v.w * v.w;
    }
#pragma unroll
    for (int o = 32; o >= 1; o >>= 1) {
        s1 += __shfl_xor(s1, o);
        s2 += __shfl_xor(s2, o);
    }
    __shared__ float sh1[4], sh2[4];
    if ((threadIdx.x & 63) == 0) { sh1[threadIdx.x >> 6] = s1; sh2[threadIdx.x >> 6] = s2; }
    __syncthreads();
    if (threadIdx.x == 0) {
        part[((size_t)c * gridDim.x + b) * 2 + 0] = sh1[0] + sh1[1] + sh1[2] + sh1[3];
        part[((size_t)c * gridDim.x + b) * 2 + 1] = sh2[0] + sh2[1] + sh2[2] + sh2[3];
    }
}

__global__ void bn_finish(const float* __restrict__ part, const float* __restrict__ g,
                          const float* __restrict__ bt, float* __restrict__ scale,
                          float* __restrict__ shift, int C, int HW, float eps) {
    const int c = blockIdx.x * 256 + threadIdx.x;
    if (c >= C) return;
    float s1 = 0.f, s2 = 0.f;
#pragma unroll
    for (int b = 0; b < NB_; ++b) {
        s1 += part[((size_t)c * NB_ + b) * 2 + 0];
        s2 += part[((size_t)c * NB_ + b) * 2 + 1];
    }
    const float invN = 1.f / (float)(NB_ * HW);
    const float m = s1 * invN;
    const float var = s2 * invN - m * m;
    const float sc = g[c] * rsqrtf(var + eps);
    scale[c] = sc;
    shift[c] = bt[c] - m * sc;
}

// ---------------- LN + split heads (k only) ----------------
__global__ void ln_split(const float* __restrict__ in, const float* __restrict__ g,
                         const float* __restrict__ bt, float* __restrict__ out,
                         int HW, int applyLN, float eps) {
    const int row = blockIdx.x * 8 + (threadIdx.x >> 5);
    const int d = threadIdx.x & 31;
    const int j = row % HW;
    const int h = (row / HW) % NHEAD;
    const int b = row / (HW * NHEAD);
    float v = in[((size_t)b * OUTCH + d * NHEAD + h) * HW + j];
    if (applyLN) {
        float s1 = v, s2 = v * v;
#pragma unroll
        for (int o = 16; o >= 1; o >>= 1) {
            s1 += __shfl_xor(s1, o, 32);
            s2 += __shfl_xor(s2, o, 32);
        }
        const float m = s1 * (1.f / 32.f);
        const float var = s2 * (1.f / 32.f) - m * m;
        v = (v - m) * rsqrtf(var + eps) * g[h * 32 + d] + bt[h * 32 + d];
    }
    out[((size_t)(b * NHEAD + h) * HW + j) * 32 + d] = v;
}

// ---------------- M = k^T v (v read directly from conv-layout v16) ----------------
__global__ void kv_outer(const float* __restrict__ kn, const float* __restrict__ v16,
                         float* __restrict__ M) {
    __shared__ float vs[256][33];
    const int bh = blockIdx.x;
    const int b = bh >> 3, h = bh & 7;
    const float* kp = kn + (size_t)bh * 256 * 32;
    const int tid = threadIdx.y * 32 + threadIdx.x;
    for (int t = tid; t < 256 * 32; t += 1024) {
        const int d = t >> 8, j = t & 255;
        vs[j][d] = v16[((size_t)(b * 256 + d * NHEAD + h)) * 256 + j];
    }
    __syncthreads();
    const int e = threadIdx.x, dd = threadIdx.y;
    float acc = 0.f;
    for (int j = 0; j < 256; ++j) acc += kp[j * 32 + e] * vs[j][dd];
    M[((size_t)bh * 32 + e) * 32 + dd] = acc;
}

// ---------------- attention out: o = (LN(q) @ M + Bv)/32, 2 px/thread, SGPR-M ----------------
// Bv2 layout: [h][qb][b*32+d]
__global__ __launch_bounds__(256, 2)
void attn_out(const float* __restrict__ q, const float* __restrict__ gq,
              const float* __restrict__ bq, const float* __restrict__ M,
              const float* __restrict__ Bv, float* __restrict__ o) {
    const int gid = blockIdx.x * 256 + threadIdx.x;
    const int ip = (gid & 2047) * 2;
    const int h  = (gid >> 11) & 7;
    const int b  = gid >> 14;

    const float* Mp = M + ((size_t)(b * NHEAD + h) << 10);
    {
        uint64_t a = (uint64_t)Mp;
        uint32_t lo = __builtin_amdgcn_readfirstlane((uint32_t)a);
        uint32_t hi = __builtin_amdgcn_readfirstlane((uint32_t)(a >> 32));
        Mp = (const float*)((((uint64_t)hi) << 32) | lo);
    }

    const float* qp = q + (size_t)b * OUTCH * 4096 + h * 4096 + ip;
    float q0[32], q1[32];
    float a1 = 0.f, a2 = 0.f, b1 = 0.f, b2 = 0.f;
#pragma unroll
    for (int d = 0; d < 32; ++d) {
        const float2 v = *reinterpret_cast<const float2*>(qp + (size_t)d * NHEAD * 4096);
        q0[d] = v.x; q1[d] = v.y;
        a1 += v.x; a2 += v.x * v.x;
        b1 += v.y; b2 += v.y * v.y;
    }
    {
        const float m0 = a1 * (1.f / 32.f);
        const float r0 = rsqrtf(a2 * (1.f / 32.f) - m0 * m0 + 1e-6f);
        const float m1 = b1 * (1.f / 32.f);
        const float r1 = rsqrtf(b2 * (1.f / 32.f) - m1 * m1 + 1e-6f);
#pragma unroll
        for (int d = 0; d < 32; ++d) {
            const float gg = gq[h * 32 + d], bb = bq[h * 32 + d];
            q0[d] = (q0[d] - m0) * r0 * gg + bb;
            q1[d] = (q1[d] - m1) * r1 * gg + bb;
        }
    }

    const int y = ip >> 6, x = ip & 63;
    const int qb0 = (y >> 2) * 16 + (x >> 2);
    const int qb1 = (y >> 2) * 16 + ((x + 1) >> 2);
    const float* Bp0 = Bv + ((size_t)h * 256 + qb0) * 256 + b * 32;
    const float* Bp1 = Bv + ((size_t)h * 256 + qb1) * 256 + b * 32;
    float acc0[32], acc1[32];
#pragma unroll
    for (int t = 0; t < 8; ++t) {
        const float4 v0 = *reinterpret_cast<const float4*>(Bp0 + t * 4);
        const float4 v1 = *reinterpret_cast<const float4*>(Bp1 + t * 4);
        acc0[t * 4 + 0] = v0.x; acc0[t * 4 + 1] = v0.y; acc0[t * 4 + 2] = v0.z; acc0[t * 4 + 3] = v0.w;
        acc1[t * 4 + 0] = v1.x; acc1[t * 4 + 1] = v1.y; acc1[t * 4 + 2] = v1.z; acc1[t * 4 + 3] = v1.w;
    }

    for (int e = 0; e < 32; ++e) {
        const float qe0 = q0[e], qe1 = q1[e];
#pragma unroll
        for (int d = 0; d < 32; ++d) {
            const float m = Mp[e * 32 + d];
            acc0[d] += qe0 * m;
            acc1[d] += qe1 * m;
        }
    }

    float* op = o + (size_t)b * OUTCH * 4096 + h * 4096 + ip;
#pragma unroll
    for (int d = 0; d < 32; ++d) {
        float2 v;
        v.x = acc0[d] * (1.f / 32.f);
        v.y = acc1[d] * (1.f / 32.f);
        *reinterpret_cast<float2*>(op + (size_t)d * NHEAD * 4096) = v;
    }
}

extern "C" void kernel_launch(void* const* d_in, const int* in_sizes, int n_in,
                              void* d_out, int out_size, void* d_ws, size_t ws_size,
                              hipStream_t stream) {
    const float* x1        = (const float*)d_in[0];
    const float* x2        = (const float*)d_in[1];
    const float* conv_ch_w = (const float*)d_in[2];
    const float* conv_ch_b = (const float*)d_in[3];
    const float* norm_l_g  = (const float*)d_in[4];
    const float* norm_l_b  = (const float*)d_in[5];
    const float* norm_h_g  = (const float*)d_in[6];
    const float* norm_h_b  = (const float*)d_in[7];
    const float* to_kv_dw  = (const float*)d_in[8];
    const float* to_kv_pw  = (const float*)d_in[9];
    const float* to_q_dw   = (const float*)d_in[10];
    const float* to_q_pw   = (const float*)d_in[11];
    const float* to_out_dw = (const float*)d_in[12];
    const float* to_out_pw = (const float*)d_in[13];
    const float* rel_table = (const float*)d_in[14];
    const float* normq_g   = (const float*)d_in[15];
    const float* normq_b   = (const float*)d_in[16];
    const float* normk_g   = (const float*)d_in[17];
    const float* normk_b   = (const float*)d_in[18];
    const float* norm2_g   = (const float*)d_in[19];
    const float* norm2_b   = (const float*)d_in[20];
    const float* mlp_w     = (const float*)d_in[21];
    float* Dout = (float*)d_out;

    float* ws = (float*)d_ws;
    const size_t NBIG = (size_t)NB_ * OUTCH * 4096;  // 8388608 floats (32 MB)
    float* X1C = ws;               // x1c kept alive: [8][256][1024] = 8 MB
    float* A   = ws + NBIG;
    float* Bb  = ws + 2 * NBIG;
    float* sm  = ws + 3 * NBIG;
    float* scale1 = sm;            float* shift1 = sm + 512;
    float* scale2 = sm + 1024;     float* shift2 = sm + 1280;
    float* scale3 = sm + 1536;     float* shift3 = sm + 1792;
    float* k16 = sm + 2048;
    float* v16 = k16 + 524288;
    float* kn  = v16 + 524288;
    float* vh  = kn  + 524288;     // (unused slot retained for layout stability)
    float* Mm  = vh  + 524288;
    float* Bv  = Mm  + 65536;      // Bv2: [h][qb][b*32+d], 524288 floats
    short* Wq  = (short*)(Bv + 524288);
    short* Wo  = Wq + 65536;
    short* Wm  = Wo + 65536;
    short* Wc  = Wm + 65536;       // conv_ch_w packed: 256x512
    short* Wkv = Wc + 131072;      // to_kv_pw packed: 512x512
    float* bnpart = (float*)(Wkv + 262144);  // 8192 floats max

    short* Xp1 = (short*)Bb;             // x1 packed: 8 MB
    short* Xp2 = (short*)Bb + 4194304;   // kv_dw packed: 8 MB
    short* Xp  = (short*)Bb;             // big packed X (16 MB), steps 8+
    short* Bmp = (short*)Bb + 8388608;   // bias matrices: 1 MB
    short* Xpv = Bmp + 524288;           // packed v^T: 1 MB
    float* kv  = A;                      // 16 MB fp32 [8,512,1024]

    // 0. pack weights + bias matrix
    pack_w<<<256, 256, 0, stream>>>(to_q_pw, Wq, 256, 256);
    pack_w<<<256, 256, 0, stream>>>(to_out_pw, Wo, 256, 256);
    pack_w<<<256, 256, 0, stream>>>(mlp_w, Wm, 256, 256);
    pack_w<<<512, 256, 0, stream>>>(conv_ch_w, Wc, 256, 512);
    pack_w<<<1024, 256, 0, stream>>>(to_kv_pw, Wkv, 512, 512);
    bias_mat<<<2048, 256, 0, stream>>>(rel_table, Bmp);

    // 1. x1 -> packed bf16; x1c = mfma(x1p, Wc) + bias -> X1C (kept alive)
    pack_tile<0><<<dim3(4, 16, 8), 256, 0, stream>>>(x1, nullptr, nullptr, Xp1, 512, 1024);
    mfma_pw<0, 0><<<dim3(16, 2, 8), 256, 0, stream>>>(Xp1, Wc, conv_ch_b, nullptr, X1C, 512, 256, 1024);
    // 3. BN stats x1 (two-phase)
    bn_stats_part<<<dim3(8, 512), 256, 0, stream>>>(x1, bnpart, 512, 1024);
    bn_finish<<<2, 256, 0, stream>>>(bnpart, norm_l_g, norm_l_b, scale1, shift1, 512, 1024, 1e-5f);
    // 4. kv_dw = dw3(BN(x1)) -> Xp2 (packed bf16)
    dw3_direct<32><<<dim3(4, 16, 8), 256, 0, stream>>>(x1, scale1, shift1, to_kv_dw, Xp2, 512, 32);
    // 5. kv = mfma(Xp2, Wkv) -> A
    mfma_pw<0, 0><<<dim3(16, 4, 8), 256, 0, stream>>>(Xp2, Wkv, nullptr, nullptr, kv, 512, 512, 1024);
    // 6. k16, v16 = resize to 16x16
    resize_bilinear<256, 32, 32, 16, 16><<<2048, 256, 0, stream>>>(kv, k16, 512 * 1024);
    resize_bilinear<256, 32, 32, 16, 16><<<2048, 256, 0, stream>>>(kv + 256 * 1024, v16, 512 * 1024);
    // 7. BN stats x2 (two-phase)
    bn_stats_part<<<dim3(8, 256), 256, 0, stream>>>(x2, bnpart, 256, 4096);
    bn_finish<<<1, 256, 0, stream>>>(bnpart, norm_h_g, norm_h_b, scale2, shift2, 256, 4096, 1e-5f);
    // 8. q_dw = dw3(BN(x2)) -> Xp (packed bf16)
    dw3_direct<64><<<dim3(16, 8, 8), 256, 0, stream>>>(x2, scale2, shift2, to_q_dw, Xp, 256, 64);
    // 9. q = mfma(Xp, Wq) -> A
    mfma_pw<0, 0><<<dim3(64, 2, 8), 256, 0, stream>>>(Xp, Wq, nullptr, nullptr, A, 256, 256, 4096);
    // 10. kn = LN(split(k16)); Xpv = packed v^T (v-split pass eliminated)
    ln_split<<<2048, 256, 0, stream>>>(k16, normk_g, normk_b, kn, 256, 1, 1e-6f);
    pack_vT<<<dim3(8, 8), 256, 0, stream>>>(v16, Xpv);
    // 11. M = k^T v (v16 read directly)
    kv_outer<<<64, dim3(32, 32), 0, stream>>>(kn, v16, Mm);
    // 12. Bv2[h][qb][b*32+d] = bias_h @ V_h  (batched MFMA GEMM)
    mfma_pw<0, 1><<<dim3(4, 2, 8), 256, 0, stream>>>(Xpv, Bmp, nullptr, nullptr, Bv, 256, 256, 256);
    // 13. o = (LN(q) @ M + Bv)/32, in-place on A
    attn_out<<<512, 256, 0, stream>>>(A, normq_g, normq_b, Mm, Bv, A);
    // 14. out_dw = dw3(o) -> Xp (packed bf16)
    dw3_direct<64><<<dim3(16, 8, 8), 256, 0, stream>>>(A, nullptr, nullptr, to_out_dw, Xp, 256, 64);
    // 15. o2 = mfma(Xp, Wo) + bilinear(X1C) -> A  (res2; residue fused in epilogue)
    mfma_pw<2, 0><<<dim3(64, 2, 8), 256, 0, stream>>>(Xp, Wo, nullptr, X1C, A, 256, 256, 4096);
    // 16. BN stats o2 (two-phase)
    bn_stats_part<<<dim3(8, 256), 256, 0, stream>>>(A, bnpart, 256, 4096);
    bn_finish<<<1, 256, 0, stream>>>(bnpart, norm2_g, norm2_b, scale3, shift3, 256, 4096, 1e-5f);
    // 17. r = relu(BN(o2)) -> Xp (packed bf16)
    pack_tile<1><<<dim3(16, 8, 8), 256, 0, stream>>>(A, scale3, shift3, Xp, 256, 4096);
    // 18. out = mfma(Xp, Wm) + res2(A) -> d_out
    mfma_pw<1, 0><<<dim3(64, 2, 8), 256, 0, stream>>>(Xp, Wm, nullptr, A, Dout, 256, 256, 4096);
}

// Round 15
// 299.608 us; speedup vs baseline: 1.2764x; 1.0105x over previous
//
#include <hip/hip_runtime.h>
#include <math.h>

#define NB_   8
#define INCH  512
#define OUTCH 256
#define NHEAD 8
#define DHEAD 32

typedef __attribute__((ext_vector_type(8))) short short8v;
typedef __attribute__((ext_vector_type(4))) short short4v;
typedef __attribute__((ext_vector_type(4))) float f32x4;

__device__ inline short f2bf(float f) {
    unsigned u = __float_as_uint(f);
    unsigned r = u + 0x7FFFu + ((u >> 16) & 1u);
    return (short)(r >> 16);
}

// ---------------- pack fp32 weight [Co][Ci] -> bf16 packed-k layout ----------------
// packed pos within 32-k tile: (q = (k%16)/4, h = k/16, r = k%4) -> q*8 + h*4 + r
__global__ void pack_w(const float* __restrict__ W, short* __restrict__ Wp, int Co, int Ci) {
    const int idx = blockIdx.x * 256 + threadIdx.x;
    if (idx >= Co * Ci) return;
    const int m = idx / Ci, i = idx % Ci;
    const int kt = i >> 5, w32 = i & 31;
    const int h = w32 >> 4, q = (w32 & 15) >> 2, r = w32 & 3;
    Wp[m * Ci + kt * 32 + q * 8 + h * 4 + r] = f2bf(W[idx]);
}

// ---------------- bias matrix: Bm[h][qb][j] packed bf16 from rel_table ----------------
__global__ void bias_mat(const float* __restrict__ rel, short* __restrict__ Bm) {
    const int idx = blockIdx.x * 256 + threadIdx.x;   // 8*256*256
    const int h  = idx >> 16;
    const int qb = (idx >> 8) & 255;
    const int pp = idx & 255;
    const int kt = pp >> 5, w = pp & 31;
    const int q = w >> 3, hh = (w >> 2) & 1, r = w & 3;
    const int j = kt * 32 + hh * 16 + q * 4 + r;
    const int qy = qb >> 4, qx = qb & 15;
    const int ky = j >> 4, kx = j & 15;
    Bm[idx] = f2bf(rel[((qy - ky + 15) * 31 + (qx - kx + 15)) * NHEAD + h]);
}

// ---------------- pack v16 (conv layout) -> Xpv[h][(b*32+d)][j packed] bf16 ----------------
__global__ void pack_vT(const float* __restrict__ v16, short* __restrict__ Xpv) {
    const int h = blockIdx.x;
    const int b = blockIdx.y;
    const int tid = threadIdx.x;
#pragma unroll
    for (int cc = 0; cc < 4; ++cc) {
        const int c  = tid * 4 + cc;      // 0..1023
        const int d  = c >> 5;
        const int ck = c & 31;
        const int kt = ck >> 2, q = ck & 3;
        const float* vp = v16 + ((size_t)(b * 256 + d * NHEAD + h)) * 256;
        short8v v;
#pragma unroll
        for (int hh = 0; hh < 2; ++hh)
#pragma unroll
            for (int r = 0; r < 4; ++r)
                v[hh * 4 + r] = f2bf(vp[kt * 32 + hh * 16 + q * 4 + r]);
        *reinterpret_cast<short8v*>(&Xpv[(size_t)h * 65536 + (b * 32 + d) * 256 + kt * 32 + q * 8]) = v;
    }
}

// ---------------- LDS-staged pack: fp32 [B][C][P] -> packed bf16 [B][P][C] ----------------
template <int BN_RELU>
__global__ __launch_bounds__(256, 4)
void pack_tile(const float* __restrict__ in, const float* __restrict__ scale,
               const float* __restrict__ shift, short* __restrict__ outp, int C, int P) {
    __shared__ float s[32][256];
    const int tid = threadIdx.x;
    const int p0 = blockIdx.x * 256;
    const int kt = blockIdx.y;
    const int b  = blockIdx.z;
#pragma unroll
    for (int c = 0; c < 32; ++c) {
        const int gc = kt * 32 + c;
        float v = in[((size_t)b * C + gc) * P + p0 + tid];
        if (BN_RELU) {
            v = v * scale[gc] + shift[gc];
            v = v > 0.f ? v : 0.f;
        }
        s[c][tid] = v;
    }
    __syncthreads();
    short* op = outp + ((size_t)b * P + p0 + tid) * C + kt * 32;
#pragma unroll
    for (int q = 0; q < 4; ++q) {
        short8v v;
#pragma unroll
        for (int h = 0; h < 2; ++h)
#pragma unroll
            for (int r = 0; r < 4; ++r)
                v[h * 4 + r] = f2bf(s[h * 16 + q * 4 + r][tid]);
        *reinterpret_cast<short8v*>(op + q * 8) = v;
    }
}

// ---------------- direct (optional BN) + depthwise 3x3 -> packed bf16 ----------------
template <int W_>
__global__ __launch_bounds__(256, 4)
void dw3_direct(const float* __restrict__ in, const float* __restrict__ scale,
                const float* __restrict__ shift, const float* __restrict__ dw,
                short* __restrict__ outp, int C, int H) {
    constexpr int XG = W_ / 8;
    constexpr int RT = 256 / W_;
    __shared__ __align__(16) short so[256][40];
    const int tid = threadIdx.x;
    const int cg  = tid & 7;
    const int pxg = tid >> 3;
    const int row = pxg / XG;
    const int xg  = pxg % XG;
    const int x0  = xg * 8;
    const int y   = blockIdx.x * RT + row;
    const int kt  = blockIdx.y;
    const int b   = blockIdx.z;
    const int P   = H * W_;

    float acc[4][8];
#pragma unroll
    for (int r = 0; r < 4; ++r)
#pragma unroll
        for (int j = 0; j < 8; ++j) acc[r][j] = 0.f;

#pragma unroll
    for (int r = 0; r < 4; ++r) {
        const int gc = kt * 32 + cg * 4 + r;
        const float sc = scale ? scale[gc] : 1.f;
        const float sh = scale ? shift[gc] : 0.f;
        const float* wp = dw + gc * 9;
#pragma unroll
        for (int dy = 0; dy < 3; ++dy) {
            const int gy = y - 1 + dy;
            if (gy < 0 || gy >= H) continue;
            const float* bp = in + ((size_t)b * C + gc) * P + gy * W_;
            float w[10];
            w[0] = (x0 > 0) ? bp[x0 - 1] : 0.f;
            const float4 m0 = *reinterpret_cast<const float4*>(bp + x0);
            const float4 m1 = *reinterpret_cast<const float4*>(bp + x0 + 4);
            w[1] = m0.x; w[2] = m0.y; w[3] = m0.z; w[4] = m0.w;
            w[5] = m1.x; w[6] = m1.y; w[7] = m1.z; w[8] = m1.w;
            w[9] = (x0 + 8 < W_) ? bp[x0 + 8] : 0.f;
            if (scale) {
#pragma unroll
                for (int t = 0; t < 10; ++t) w[t] = w[t] * sc + sh;
                if (x0 == 0) w[0] = 0.f;
                if (x0 + 8 >= W_) w[9] = 0.f;
            }
            const float t0 = wp[dy * 3 + 0], t1 = wp[dy * 3 + 1], t2 = wp[dy * 3 + 2];
#pragma unroll
            for (int j = 0; j < 8; ++j)
                acc[r][j] += t0 * w[j] + t1 * w[j + 1] + t2 * w[j + 2];
        }
    }

    const int posb = (cg & 3) * 8 + (cg >> 2) * 4;
#pragma unroll
    for (int j = 0; j < 8; ++j) {
        short4v v;
#pragma unroll
        for (int r = 0; r < 4; ++r) v[r] = f2bf(acc[r][j]);
        *reinterpret_cast<short4v*>(&so[pxg * 8 + j][posb]) = v;
    }
    __syncthreads();
    short* op = outp + ((size_t)b * P + blockIdx.x * 256 + tid) * C + kt * 32;
#pragma unroll
    for (int q = 0; q < 4; ++q)
        *reinterpret_cast<short8v*>(op + q * 8) = *reinterpret_cast<const short8v*>(&so[tid][q * 8]);
}

// ---------------- MFMA bf16 GEMM: out[z,m,p] = sum_i W[m,i] X[z,i,p] ----------------
// BM=128, BN=64, BK=64 (two 32-k tiles per barrier); 4 waves (2x2), wave tile 64x32.
// RES_MODE: 0 none, 1 plain residual, 2 bilinear-upsampled residual from x1c [B][Co][32*32].
template <int RES_MODE, int BATCH_W>
__global__ __launch_bounds__(256, 4)
void mfma_pw(const short* __restrict__ Xp, const short* __restrict__ Wp,
             const float* __restrict__ bias, const float* __restrict__ res,
             float* __restrict__ out, int Ci, int Co, int P) {
    __shared__ short Ash[8192];  // [half2][q4][m128][8] = 16KB
    __shared__ short Bsh[4096];  // [half2][q4][n64][8]  = 8KB
    const int b   = blockIdx.z;
    const int m0  = blockIdx.y * 128;
    const int n0  = blockIdx.x * 64;
    const int tid = threadIdx.x;
    const int lane = tid & 63;
    const int wid  = tid >> 6;
    const int wr = wid >> 1, wc = wid & 1;
    const int ql = lane >> 4, l16 = lane & 15;

    f32x4 acc[4][2];
#pragma unroll
    for (int mb = 0; mb < 4; ++mb)
#pragma unroll
        for (int nb = 0; nb < 2; ++nb) acc[mb][nb] = (f32x4){0.f, 0.f, 0.f, 0.f};

    const size_t wbase = (BATCH_W ? (size_t)b * Co * Ci : 0);
    const size_t xbase = (size_t)b * P * Ci;

    const int nkt2 = Ci >> 6;   // K/64 steps
    for (int kt = 0; kt < nkt2; ++kt) {
        const int kof = kt * 64;
        // A: 1024 chunks of 16B (2 halves x 4 q x 128 rows)
#pragma unroll
        for (int s = 0; s < 4; ++s) {
            const int c  = tid + s * 256;
            const int rr = c & 127, q8 = c >> 7;
            const int kti = q8 >> 2, qq = q8 & 3;
            __builtin_amdgcn_global_load_lds(
                Wp + wbase + (size_t)(m0 + rr) * Ci + kof + kti * 32 + qq * 8,
                &Ash[(kti * 512 + qq * 128 + rr) * 8], 16, 0, 0);
        }
        // B: 512 chunks (2 halves x 4 q x 64 rows)
#pragma unroll
        for (int s = 0; s < 2; ++s) {
            const int c  = tid + s * 256;
            const int rr = c & 63, q8 = c >> 6;
            const int kti = q8 >> 2, qq = q8 & 3;
            __builtin_amdgcn_global_load_lds(
                Xp + xbase + (size_t)(n0 + rr) * Ci + kof + kti * 32 + qq * 8,
                &Bsh[(kti * 256 + qq * 64 + rr) * 8], 16, 0, 0);
        }
        __syncthreads();

#pragma unroll
        for (int half = 0; half < 2; ++half) {
            short8v a[4], bf[2];
#pragma unroll
            for (int mb = 0; mb < 4; ++mb)
                a[mb] = *reinterpret_cast<const short8v*>(
                    &Ash[(half * 512 + ql * 128 + wr * 64 + mb * 16 + l16) * 8]);
#pragma unroll
            for (int nb = 0; nb < 2; ++nb)
                bf[nb] = *reinterpret_cast<const short8v*>(
                    &Bsh[(half * 256 + ql * 64 + wc * 32 + nb * 16 + l16) * 8]);
#pragma unroll
            for (int mb = 0; mb < 4; ++mb)
#pragma unroll
                for (int nb = 0; nb < 2; ++nb)
                    acc[mb][nb] = __builtin_amdgcn_mfma_f32_16x16x32_bf16(a[mb], bf[nb], acc[mb][nb], 0, 0, 0);
        }
        __syncthreads();
    }

#pragma unroll
    for (int mb = 0; mb < 4; ++mb) {
        const int row = m0 + wr * 64 + mb * 16 + ql * 4;
#pragma unroll
        for (int nb = 0; nb < 2; ++nb) {
            const int col = n0 + wc * 32 + nb * 16 + l16;
            const size_t base = ((size_t)b * Co + row) * P + col;
            // bilinear params for RES_MODE==2 (out 64x64 from 32x32, linspace endpoints)
            int ry0 = 0, ry1 = 0, rx0 = 0, rx1 = 0; float rwy = 0.f, rwx = 0.f;
            if (RES_MODE == 2) {
                const int yy = col >> 6, xx = col & 63;
                const float fy = (float)yy * (31.f / 63.f);
                const float fx = (float)xx * (31.f / 63.f);
                ry0 = (int)fy; ry1 = min(ry0 + 1, 31); rwy = fy - (float)ry0;
                rx0 = (int)fx; rx1 = min(rx0 + 1, 31); rwx = fx - (float)rx0;
            }
#pragma unroll
            for (int j = 0; j < 4; ++j) {
                float v = acc[mb][nb][j];
                if (bias) v += bias[row + j];
                if (RES_MODE == 1) v += res[base + (size_t)j * P];
                if (RES_MODE == 2) {
                    const float* pl = res + ((size_t)b * Co + row + j) * 1024;
                    const float r0 = pl[ry0 * 32 + rx0] * (1.f - rwx) + pl[ry0 * 32 + rx1] * rwx;
                    const float r1 = pl[ry1 * 32 + rx0] * (1.f - rwx) + pl[ry1 * 32 + rx1] * rwx;
                    v += r0 * (1.f - rwy) + r1 * rwy;
                }
                out[base + (size_t)j * P] = v;
            }
        }
    }
}

// ---------------- bilinear resize (compile-time dims; all pow2) ----------------
template <int C, int Hi, int Wi, int Ho, int Wo>
__global__ void resize_bilinear(const float* __restrict__ in, float* __restrict__ out, int ibs) {
    const int idx = blockIdx.x * 256 + threadIdx.x;
    const int x = idx & (Wo - 1);
    const int y = (idx / Wo) & (Ho - 1);
    const int c = (idx / (Wo * Ho)) & (C - 1);
    const int b = idx / (Wo * Ho * C);
    const float fy = (float)y * (float)(Hi - 1) / (float)(Ho - 1);
    const float fx = (float)x * (float)(Wi - 1) / (float)(Wo - 1);
    int y0 = (int)floorf(fy); int y1 = min(y0 + 1, Hi - 1); const float wy = fy - (float)y0;
    int x0 = (int)floorf(fx); int x1 = min(x0 + 1, Wi - 1); const float wx = fx - (float)x0;
    const float* pc = in + (size_t)b * ibs + (size_t)c * Hi * Wi;
    const float r0 = pc[y0 * Wi + x0] * (1.f - wx) + pc[y0 * Wi + x1] * wx;
    const float r1 = pc[y1 * Wi + x0] * (1.f - wx) + pc[y1 * Wi + x1] * wx;
    out[idx] = r0 * (1.f - wy) + r1 * wy;
}

// ---------------- BN stats, two-phase ----------------
__global__ __launch_bounds__(256, 8)
void bn_stats_part(const float* __restrict__ in, float* __restrict__ part, int C, int HW) {
    const int b = blockIdx.x;
    const int c = blockIdx.y;
    const float* p = in + ((size_t)b * C + c) * HW;
    float s1 = 0.f, s2 = 0.f;
    for (int i = threadIdx.x * 4; i < HW; i += 1024) {
        const float4 v = *reinterpret_cast<const float4*>(p + i);
        s1 += v.x + v.y + v.z + v.w;
        s2 += v.x * v.x + v.y * v.y + v.z * v.z + v.w * v.w;
    }
#pragma unroll
    for (int o = 32; o >= 1; o >>= 1) {
        s1 += __shfl_xor(s1, o);
        s2 += __shfl_xor(s2, o);
    }
    __shared__ float sh1[4], sh2[4];
    if ((threadIdx.x & 63) == 0) { sh1[threadIdx.x >> 6] = s1; sh2[threadIdx.x >> 6] = s2; }
    __syncthreads();
    if (threadIdx.x == 0) {
        part[((size_t)c * gridDim.x + b) * 2 + 0] = sh1[0] + sh1[1] + sh1[2] + sh1[3];
        part[((size_t)c * gridDim.x + b) * 2 + 1] = sh2[0] + sh2[1] + sh2[2] + sh2[3];
    }
}

__global__ void bn_finish(const float* __restrict__ part, const float* __restrict__ g,
                          const float* __restrict__ bt, float* __restrict__ scale,
                          float* __restrict__ shift, int C, int HW, float eps) {
    const int c = blockIdx.x * 256 + threadIdx.x;
    if (c >= C) return;
    float s1 = 0.f, s2 = 0.f;
#pragma unroll
    for (int b = 0; b < NB_; ++b) {
        s1 += part[((size_t)c * NB_ + b) * 2 + 0];
        s2 += part[((size_t)c * NB_ + b) * 2 + 1];
    }
    const float invN = 1.f / (float)(NB_ * HW);
    const float m = s1 * invN;
    const float var = s2 * invN - m * m;
    const float sc = g[c] * rsqrtf(var + eps);
    scale[c] = sc;
    shift[c] = bt[c] - m * sc;
}

// ---------------- LN + split heads (k only) ----------------
__global__ void ln_split(const float* __restrict__ in, const float* __restrict__ g,
                         const float* __restrict__ bt, float* __restrict__ out,
                         int HW, int applyLN, float eps) {
    const int row = blockIdx.x * 8 + (threadIdx.x >> 5);
    const int d = threadIdx.x & 31;
    const int j = row % HW;
    const int h = (row / HW) % NHEAD;
    const int b = row / (HW * NHEAD);
    float v = in[((size_t)b * OUTCH + d * NHEAD + h) * HW + j];
    if (applyLN) {
        float s1 = v, s2 = v * v;
#pragma unroll
        for (int o = 16; o >= 1; o >>= 1) {
            s1 += __shfl_xor(s1, o, 32);
            s2 += __shfl_xor(s2, o, 32);
        }
        const float m = s1 * (1.f / 32.f);
        const float var = s2 * (1.f / 32.f) - m * m;
        v = (v - m) * rsqrtf(var + eps) * g[h * 32 + d] + bt[h * 32 + d];
    }
    out[((size_t)(b * NHEAD + h) * HW + j) * 32 + d] = v;
}

// ---------------- M = k^T v (v read directly from conv-layout v16) ----------------
__global__ void kv_outer(const float* __restrict__ kn, const float* __restrict__ v16,
                         float* __restrict__ M) {
    __shared__ float vs[256][33];
    const int bh = blockIdx.x;
    const int b = bh >> 3, h = bh & 7;
    const float* kp = kn + (size_t)bh * 256 * 32;
    const int tid = threadIdx.y * 32 + threadIdx.x;
    for (int t = tid; t < 256 * 32; t += 1024) {
        const int d = t >> 8, j = t & 255;
        vs[j][d] = v16[((size_t)(b * 256 + d * NHEAD + h)) * 256 + j];
    }
    __syncthreads();
    const int e = threadIdx.x, dd = threadIdx.y;
    float acc = 0.f;
    for (int j = 0; j < 256; ++j) acc += kp[j * 32 + e] * vs[j][dd];
    M[((size_t)bh * 32 + e) * 32 + dd] = acc;
}

// ---------------- attention out: o = (LN(q) @ M + Bv)/32, 2 px/thread, SGPR-M ----------------
// Bv2 layout: [h][qb][b*32+d]
__global__ __launch_bounds__(256, 2)
void attn_out(const float* __restrict__ q, const float* __restrict__ gq,
              const float* __restrict__ bq, const float* __restrict__ M,
              const float* __restrict__ Bv, float* __restrict__ o) {
    const int gid = blockIdx.x * 256 + threadIdx.x;
    const int ip = (gid & 2047) * 2;
    const int h  = (gid >> 11) & 7;
    const int b  = gid >> 14;

    const float* Mp = M + ((size_t)(b * NHEAD + h) << 10);
    {
        uint64_t a = (uint64_t)Mp;
        uint32_t lo = __builtin_amdgcn_readfirstlane((uint32_t)a);
        uint32_t hi = __builtin_amdgcn_readfirstlane((uint32_t)(a >> 32));
        Mp = (const float*)((((uint64_t)hi) << 32) | lo);
    }

    const float* qp = q + (size_t)b * OUTCH * 4096 + h * 4096 + ip;
    float q0[32], q1[32];
    float a1 = 0.f, a2 = 0.f, b1 = 0.f, b2 = 0.f;
#pragma unroll
    for (int d = 0; d < 32; ++d) {
        const float2 v = *reinterpret_cast<const float2*>(qp + (size_t)d * NHEAD * 4096);
        q0[d] = v.x; q1[d] = v.y;
        a1 += v.x; a2 += v.x * v.x;
        b1 += v.y; b2 += v.y * v.y;
    }
    {
        const float m0 = a1 * (1.f / 32.f);
        const float r0 = rsqrtf(a2 * (1.f / 32.f) - m0 * m0 + 1e-6f);
        const float m1 = b1 * (1.f / 32.f);
        const float r1 = rsqrtf(b2 * (1.f / 32.f) - m1 * m1 + 1e-6f);
#pragma unroll
        for (int d = 0; d < 32; ++d) {
            const float gg = gq[h * 32 + d], bb = bq[h * 32 + d];
            q0[d] = (q0[d] - m0) * r0 * gg + bb;
            q1[d] = (q1[d] - m1) * r1 * gg + bb;
        }
    }

    const int y = ip >> 6, x = ip & 63;
    const int qb0 = (y >> 2) * 16 + (x >> 2);
    const int qb1 = (y >> 2) * 16 + ((x + 1) >> 2);
    const float* Bp0 = Bv + ((size_t)h * 256 + qb0) * 256 + b * 32;
    const float* Bp1 = Bv + ((size_t)h * 256 + qb1) * 256 + b * 32;
    float acc0[32], acc1[32];
#pragma unroll
    for (int t = 0; t < 8; ++t) {
        const float4 v0 = *reinterpret_cast<const float4*>(Bp0 + t * 4);
        const float4 v1 = *reinterpret_cast<const float4*>(Bp1 + t * 4);
        acc0[t * 4 + 0] = v0.x; acc0[t * 4 + 1] = v0.y; acc0[t * 4 + 2] = v0.z; acc0[t * 4 + 3] = v0.w;
        acc1[t * 4 + 0] = v1.x; acc1[t * 4 + 1] = v1.y; acc1[t * 4 + 2] = v1.z; acc1[t * 4 + 3] = v1.w;
    }

    for (int e = 0; e < 32; ++e) {
        const float qe0 = q0[e], qe1 = q1[e];
#pragma unroll
        for (int d = 0; d < 32; ++d) {
            const float m = Mp[e * 32 + d];
            acc0[d] += qe0 * m;
            acc1[d] += qe1 * m;
        }
    }

    float* op = o + (size_t)b * OUTCH * 4096 + h * 4096 + ip;
#pragma unroll
    for (int d = 0; d < 32; ++d) {
        float2 v;
        v.x = acc0[d] * (1.f / 32.f);
        v.y = acc1[d] * (1.f / 32.f);
        *reinterpret_cast<float2*>(op + (size_t)d * NHEAD * 4096) = v;
    }
}

extern "C" void kernel_launch(void* const* d_in, const int* in_sizes, int n_in,
                              void* d_out, int out_size, void* d_ws, size_t ws_size,
                              hipStream_t stream) {
    const float* x1        = (const float*)d_in[0];
    const float* x2        = (const float*)d_in[1];
    const float* conv_ch_w = (const float*)d_in[2];
    const float* conv_ch_b = (const float*)d_in[3];
    const float* norm_l_g  = (const float*)d_in[4];
    const float* norm_l_b  = (const float*)d_in[5];
    const float* norm_h_g  = (const float*)d_in[6];
    const float* norm_h_b  = (const float*)d_in[7];
    const float* to_kv_dw  = (const float*)d_in[8];
    const float* to_kv_pw  = (const float*)d_in[9];
    const float* to_q_dw   = (const float*)d_in[10];
    const float* to_q_pw   = (const float*)d_in[11];
    const float* to_out_dw = (const float*)d_in[12];
    const float* to_out_pw = (const float*)d_in[13];
    const float* rel_table = (const float*)d_in[14];
    const float* normq_g   = (const float*)d_in[15];
    const float* normq_b   = (const float*)d_in[16];
    const float* normk_g   = (const float*)d_in[17];
    const float* normk_b   = (const float*)d_in[18];
    const float* norm2_g   = (const float*)d_in[19];
    const float* norm2_b   = (const float*)d_in[20];
    const float* mlp_w     = (const float*)d_in[21];
    float* Dout = (float*)d_out;

    float* ws = (float*)d_ws;
    const size_t NBIG = (size_t)NB_ * OUTCH * 4096;  // 8388608 floats (32 MB)
    float* X1C = ws;               // x1c kept alive: [8][256][1024] = 8 MB
    float* A   = ws + NBIG;
    float* Bb  = ws + 2 * NBIG;
    float* sm  = ws + 3 * NBIG;
    float* scale1 = sm;            float* shift1 = sm + 512;
    float* scale2 = sm + 1024;     float* shift2 = sm + 1280;
    float* scale3 = sm + 1536;     float* shift3 = sm + 1792;
    float* k16 = sm + 2048;
    float* v16 = k16 + 524288;
    float* kn  = v16 + 524288;
    float* vh  = kn  + 524288;     // (unused slot retained for layout stability)
    float* Mm  = vh  + 524288;
    float* Bv  = Mm  + 65536;      // Bv2: [h][qb][b*32+d], 524288 floats
    short* Wq  = (short*)(Bv + 524288);
    short* Wo  = Wq + 65536;
    short* Wm  = Wo + 65536;
    short* Wc  = Wm + 65536;       // conv_ch_w packed: 256x512
    short* Wkv = Wc + 131072;      // to_kv_pw packed: 512x512
    float* bnpart = (float*)(Wkv + 262144);  // 8192 floats max

    short* Xp1 = (short*)Bb;             // x1 packed: 8 MB
    short* Xp2 = (short*)Bb + 4194304;   // kv_dw packed: 8 MB
    short* Xp  = (short*)Bb;             // big packed X (16 MB), steps 8+
    short* Bmp = (short*)Bb + 8388608;   // bias matrices: 1 MB
    short* Xpv = Bmp + 524288;           // packed v^T: 1 MB
    float* kv  = A;                      // 16 MB fp32 [8,512,1024]

    // 0. pack weights + bias matrix
    pack_w<<<256, 256, 0, stream>>>(to_q_pw, Wq, 256, 256);
    pack_w<<<256, 256, 0, stream>>>(to_out_pw, Wo, 256, 256);
    pack_w<<<256, 256, 0, stream>>>(mlp_w, Wm, 256, 256);
    pack_w<<<512, 256, 0, stream>>>(conv_ch_w, Wc, 256, 512);
    pack_w<<<1024, 256, 0, stream>>>(to_kv_pw, Wkv, 512, 512);
    bias_mat<<<2048, 256, 0, stream>>>(rel_table, Bmp);

    // 1. x1 -> packed bf16; x1c = mfma(x1p, Wc) + bias -> X1C (kept alive)
    pack_tile<0><<<dim3(4, 16, 8), 256, 0, stream>>>(x1, nullptr, nullptr, Xp1, 512, 1024);
    mfma_pw<0, 0><<<dim3(16, 2, 8), 256, 0, stream>>>(Xp1, Wc, conv_ch_b, nullptr, X1C, 512, 256, 1024);
    // 3. BN stats x1 (two-phase)
    bn_stats_part<<<dim3(8, 512), 256, 0, stream>>>(x1, bnpart, 512, 1024);
    bn_finish<<<2, 256, 0, stream>>>(bnpart, norm_l_g, norm_l_b, scale1, shift1, 512, 1024, 1e-5f);
    // 4. kv_dw = dw3(BN(x1)) -> Xp2 (packed bf16)
    dw3_direct<32><<<dim3(4, 16, 8), 256, 0, stream>>>(x1, scale1, shift1, to_kv_dw, Xp2, 512, 32);
    // 5. kv = mfma(Xp2, Wkv) -> A
    mfma_pw<0, 0><<<dim3(16, 4, 8), 256, 0, stream>>>(Xp2, Wkv, nullptr, nullptr, kv, 512, 512, 1024);
    // 6. k16, v16 = resize to 16x16
    resize_bilinear<256, 32, 32, 16, 16><<<2048, 256, 0, stream>>>(kv, k16, 512 * 1024);
    resize_bilinear<256, 32, 32, 16, 16><<<2048, 256, 0, stream>>>(kv + 256 * 1024, v16, 512 * 1024);
    // 7. BN stats x2 (two-phase)
    bn_stats_part<<<dim3(8, 256), 256, 0, stream>>>(x2, bnpart, 256, 4096);
    bn_finish<<<1, 256, 0, stream>>>(bnpart, norm_h_g, norm_h_b, scale2, shift2, 256, 4096, 1e-5f);
    // 8. q_dw = dw3(BN(x2)) -> Xp (packed bf16)
    dw3_direct<64><<<dim3(16, 8, 8), 256, 0, stream>>>(x2, scale2, shift2, to_q_dw, Xp, 256, 64);
    // 9. q = mfma(Xp, Wq) -> A
    mfma_pw<0, 0><<<dim3(64, 2, 8), 256, 0, stream>>>(Xp, Wq, nullptr, nullptr, A, 256, 256, 4096);
    // 10. kn = LN(split(k16)); Xpv = packed v^T
    ln_split<<<2048, 256, 0, stream>>>(k16, normk_g, normk_b, kn, 256, 1, 1e-6f);
    pack_vT<<<dim3(8, 8), 256, 0, stream>>>(v16, Xpv);
    // 11. M = k^T v (v16 read directly)
    kv_outer<<<64, dim3(32, 32), 0, stream>>>(kn, v16, Mm);
    // 12. Bv2[h][qb][b*32+d] = bias_h @ V_h  (batched MFMA GEMM)
    mfma_pw<0, 1><<<dim3(4, 2, 8), 256, 0, stream>>>(Xpv, Bmp, nullptr, nullptr, Bv, 256, 256, 256);
    // 13. o = (LN(q) @ M + Bv)/32, in-place on A
    attn_out<<<512, 256, 0, stream>>>(A, normq_g, normq_b, Mm, Bv, A);
    // 14. out_dw = dw3(o) -> Xp (packed bf16)
    dw3_direct<64><<<dim3(16, 8, 8), 256, 0, stream>>>(A, nullptr, nullptr, to_out_dw, Xp, 256, 64);
    // 15. o2 = mfma(Xp, Wo) + bilinear(X1C) -> A  (res2; residue fused in epilogue)
    mfma_pw<2, 0><<<dim3(64, 2, 8), 256, 0, stream>>>(Xp, Wo, nullptr, X1C, A, 256, 256, 4096);
    // 16. BN stats o2 (two-phase)
    bn_stats_part<<<dim3(8, 256), 256, 0, stream>>>(A, bnpart, 256, 4096);
    bn_finish<<<1, 256, 0, stream>>>(bnpart, norm2_g, norm2_b, scale3, shift3, 256, 4096, 1e-5f);
    // 17. r = relu(BN(o2)) -> Xp (packed bf16)
    pack_tile<1><<<dim3(16, 8, 8), 256, 0, stream>>>(A, scale3, shift3, Xp, 256, 4096);
    // 18. out = mfma(Xp, Wm) + res2(A) -> d_out
    mfma_pw<1, 0><<<dim3(64, 2, 8), 256, 0, stream>>>(Xp, Wm, nullptr, A, Dout, 256, 256, 4096);
}

// Round 16
// 290.535 us; speedup vs baseline: 1.3163x; 1.0312x over previous
//
#include <hip/hip_runtime.h>
#include <math.h>

#define NB_   8
#define INCH  512
#define OUTCH 256
#define NHEAD 8
#define DHEAD 32

typedef __attribute__((ext_vector_type(8))) short short8v;
typedef __attribute__((ext_vector_type(4))) short short4v;
typedef __attribute__((ext_vector_type(4))) float f32x4;

__device__ inline short f2bf(float f) {
    unsigned u = __float_as_uint(f);
    unsigned r = u + 0x7FFFu + ((u >> 16) & 1u);
    return (short)(r >> 16);
}

// packed pos within 32-k tile: (q = (k%16)/4, h = k/16, r = k%4) -> q*8 + h*4 + r
__device__ inline void pack_w_elem(const float* __restrict__ W, short* __restrict__ Wp,
                                   int Ci, int idx) {
    const int m = idx / Ci, i = idx % Ci;
    const int kt = i >> 5, w32 = i & 31;
    const int h = w32 >> 4, q = (w32 & 15) >> 2, r = w32 & 3;
    Wp[m * Ci + kt * 32 + q * 8 + h * 4 + r] = f2bf(W[idx]);
}

// ---------------- fused setup: pack 5 weights + bias matrix (one dispatch) ----------------
__global__ void pack_all(const float* __restrict__ q_pw, const float* __restrict__ o_pw,
                         const float* __restrict__ m_pw, const float* __restrict__ c_pw,
                         const float* __restrict__ kv_pw, const float* __restrict__ rel,
                         short* __restrict__ Wq, short* __restrict__ Wo, short* __restrict__ Wm,
                         short* __restrict__ Wc, short* __restrict__ Wkv, short* __restrict__ Bm) {
    const int blk = blockIdx.x;
    if (blk < 256) {
        pack_w_elem(q_pw, Wq, 256, blk * 256 + threadIdx.x);
    } else if (blk < 512) {
        pack_w_elem(o_pw, Wo, 256, (blk - 256) * 256 + threadIdx.x);
    } else if (blk < 768) {
        pack_w_elem(m_pw, Wm, 256, (blk - 512) * 256 + threadIdx.x);
    } else if (blk < 1280) {
        pack_w_elem(c_pw, Wc, 512, (blk - 768) * 256 + threadIdx.x);
    } else if (blk < 2304) {
        pack_w_elem(kv_pw, Wkv, 512, (blk - 1280) * 256 + threadIdx.x);
    } else {
        const int idx = (blk - 2304) * 256 + threadIdx.x;   // 8*256*256
        const int h  = idx >> 16;
        const int qb = (idx >> 8) & 255;
        const int pp = idx & 255;
        const int kt = pp >> 5, w = pp & 31;
        const int q = w >> 3, hh = (w >> 2) & 1, r = w & 3;
        const int j = kt * 32 + hh * 16 + q * 4 + r;
        const int qy = qb >> 4, qx = qb & 15;
        const int ky = j >> 4, kx = j & 15;
        Bm[idx] = f2bf(rel[((qy - ky + 15) * 31 + (qx - kx + 15)) * NHEAD + h]);
    }
}

// ---------------- LDS-staged pack: fp32 [B][C][P] -> packed bf16 [B][P][C] ----------------
template <int BN_RELU>
__global__ __launch_bounds__(256, 4)
void pack_tile(const float* __restrict__ in, const float* __restrict__ scale,
               const float* __restrict__ shift, short* __restrict__ outp, int C, int P) {
    __shared__ float s[32][256];
    const int tid = threadIdx.x;
    const int p0 = blockIdx.x * 256;
    const int kt = blockIdx.y;
    const int b  = blockIdx.z;
#pragma unroll
    for (int c = 0; c < 32; ++c) {
        const int gc = kt * 32 + c;
        float v = in[((size_t)b * C + gc) * P + p0 + tid];
        if (BN_RELU) {
            v = v * scale[gc] + shift[gc];
            v = v > 0.f ? v : 0.f;
        }
        s[c][tid] = v;
    }
    __syncthreads();
    short* op = outp + ((size_t)b * P + p0 + tid) * C + kt * 32;
#pragma unroll
    for (int q = 0; q < 4; ++q) {
        short8v v;
#pragma unroll
        for (int h = 0; h < 2; ++h)
#pragma unroll
            for (int r = 0; r < 4; ++r)
                v[h * 4 + r] = f2bf(s[h * 16 + q * 4 + r][tid]);
        *reinterpret_cast<short8v*>(op + q * 8) = v;
    }
}

// ---------------- direct (optional BN) + depthwise 3x3 -> packed bf16 ----------------
template <int W_>
__global__ __launch_bounds__(256, 4)
void dw3_direct(const float* __restrict__ in, const float* __restrict__ scale,
                const float* __restrict__ shift, const float* __restrict__ dw,
                short* __restrict__ outp, int C, int H) {
    constexpr int XG = W_ / 8;
    constexpr int RT = 256 / W_;
    __shared__ __align__(16) short so[256][40];
    const int tid = threadIdx.x;
    const int cg  = tid & 7;
    const int pxg = tid >> 3;
    const int row = pxg / XG;
    const int xg  = pxg % XG;
    const int x0  = xg * 8;
    const int y   = blockIdx.x * RT + row;
    const int kt  = blockIdx.y;
    const int b   = blockIdx.z;
    const int P   = H * W_;

    float acc[4][8];
#pragma unroll
    for (int r = 0; r < 4; ++r)
#pragma unroll
        for (int j = 0; j < 8; ++j) acc[r][j] = 0.f;

#pragma unroll
    for (int r = 0; r < 4; ++r) {
        const int gc = kt * 32 + cg * 4 + r;
        const float sc = scale ? scale[gc] : 1.f;
        const float sh = scale ? shift[gc] : 0.f;
        const float* wp = dw + gc * 9;
#pragma unroll
        for (int dy = 0; dy < 3; ++dy) {
            const int gy = y - 1 + dy;
            if (gy < 0 || gy >= H) continue;
            const float* bp = in + ((size_t)b * C + gc) * P + gy * W_;
            float w[10];
            w[0] = (x0 > 0) ? bp[x0 - 1] : 0.f;
            const float4 m0 = *reinterpret_cast<const float4*>(bp + x0);
            const float4 m1 = *reinterpret_cast<const float4*>(bp + x0 + 4);
            w[1] = m0.x; w[2] = m0.y; w[3] = m0.z; w[4] = m0.w;
            w[5] = m1.x; w[6] = m1.y; w[7] = m1.z; w[8] = m1.w;
            w[9] = (x0 + 8 < W_) ? bp[x0 + 8] : 0.f;
            if (scale) {
#pragma unroll
                for (int t = 0; t < 10; ++t) w[t] = w[t] * sc + sh;
                if (x0 == 0) w[0] = 0.f;
                if (x0 + 8 >= W_) w[9] = 0.f;
            }
            const float t0 = wp[dy * 3 + 0], t1 = wp[dy * 3 + 1], t2 = wp[dy * 3 + 2];
#pragma unroll
            for (int j = 0; j < 8; ++j)
                acc[r][j] += t0 * w[j] + t1 * w[j + 1] + t2 * w[j + 2];
        }
    }

    const int posb = (cg & 3) * 8 + (cg >> 2) * 4;
#pragma unroll
    for (int j = 0; j < 8; ++j) {
        short4v v;
#pragma unroll
        for (int r = 0; r < 4; ++r) v[r] = f2bf(acc[r][j]);
        *reinterpret_cast<short4v*>(&so[pxg * 8 + j][posb]) = v;
    }
    __syncthreads();
    short* op = outp + ((size_t)b * P + blockIdx.x * 256 + tid) * C + kt * 32;
#pragma unroll
    for (int q = 0; q < 4; ++q)
        *reinterpret_cast<short8v*>(op + q * 8) = *reinterpret_cast<const short8v*>(&so[tid][q * 8]);
}

// ---------------- MFMA bf16 GEMM: out[z,m,p] = sum_i W[m,i] X[z,i,p] ----------------
// BM=128, BN=64, BK=64 (two 32-k tiles per barrier); 4 waves (2x2), wave tile 64x32.
// RES_MODE: 0 none, 1 plain residual, 2 bilinear-upsampled residual from x1c [B][Co][32*32].
template <int RES_MODE, int BATCH_W>
__global__ __launch_bounds__(256, 4)
void mfma_pw(const short* __restrict__ Xp, const short* __restrict__ Wp,
             const float* __restrict__ bias, const float* __restrict__ res,
             float* __restrict__ out, int Ci, int Co, int P) {
    __shared__ short Ash[8192];  // [half2][q4][m128][8] = 16KB
    __shared__ short Bsh[4096];  // [half2][q4][n64][8]  = 8KB
    const int b   = blockIdx.z;
    const int m0  = blockIdx.y * 128;
    const int n0  = blockIdx.x * 64;
    const int tid = threadIdx.x;
    const int lane = tid & 63;
    const int wid  = tid >> 6;
    const int wr = wid >> 1, wc = wid & 1;
    const int ql = lane >> 4, l16 = lane & 15;

    f32x4 acc[4][2];
#pragma unroll
    for (int mb = 0; mb < 4; ++mb)
#pragma unroll
        for (int nb = 0; nb < 2; ++nb) acc[mb][nb] = (f32x4){0.f, 0.f, 0.f, 0.f};

    const size_t wbase = (BATCH_W ? (size_t)b * Co * Ci : 0);
    const size_t xbase = (size_t)b * P * Ci;

    const int nkt2 = Ci >> 6;   // K/64 steps
    for (int kt = 0; kt < nkt2; ++kt) {
        const int kof = kt * 64;
#pragma unroll
        for (int s = 0; s < 4; ++s) {
            const int c  = tid + s * 256;
            const int rr = c & 127, q8 = c >> 7;
            const int kti = q8 >> 2, qq = q8 & 3;
            __builtin_amdgcn_global_load_lds(
                Wp + wbase + (size_t)(m0 + rr) * Ci + kof + kti * 32 + qq * 8,
                &Ash[(kti * 512 + qq * 128 + rr) * 8], 16, 0, 0);
        }
#pragma unroll
        for (int s = 0; s < 2; ++s) {
            const int c  = tid + s * 256;
            const int rr = c & 63, q8 = c >> 6;
            const int kti = q8 >> 2, qq = q8 & 3;
            __builtin_amdgcn_global_load_lds(
                Xp + xbase + (size_t)(n0 + rr) * Ci + kof + kti * 32 + qq * 8,
                &Bsh[(kti * 256 + qq * 64 + rr) * 8], 16, 0, 0);
        }
        __syncthreads();

#pragma unroll
        for (int half = 0; half < 2; ++half) {
            short8v a[4], bf[2];
#pragma unroll
            for (int mb = 0; mb < 4; ++mb)
                a[mb] = *reinterpret_cast<const short8v*>(
                    &Ash[(half * 512 + ql * 128 + wr * 64 + mb * 16 + l16) * 8]);
#pragma unroll
            for (int nb = 0; nb < 2; ++nb)
                bf[nb] = *reinterpret_cast<const short8v*>(
                    &Bsh[(half * 256 + ql * 64 + wc * 32 + nb * 16 + l16) * 8]);
#pragma unroll
            for (int mb = 0; mb < 4; ++mb)
#pragma unroll
                for (int nb = 0; nb < 2; ++nb)
                    acc[mb][nb] = __builtin_amdgcn_mfma_f32_16x16x32_bf16(a[mb], bf[nb], acc[mb][nb], 0, 0, 0);
        }
        __syncthreads();
    }

#pragma unroll
    for (int mb = 0; mb < 4; ++mb) {
        const int row = m0 + wr * 64 + mb * 16 + ql * 4;
#pragma unroll
        for (int nb = 0; nb < 2; ++nb) {
            const int col = n0 + wc * 32 + nb * 16 + l16;
            const size_t base = ((size_t)b * Co + row) * P + col;
            int ry0 = 0, ry1 = 0, rx0 = 0, rx1 = 0; float rwy = 0.f, rwx = 0.f;
            if (RES_MODE == 2) {
                const int yy = col >> 6, xx = col & 63;
                const float fy = (float)yy * (31.f / 63.f);
                const float fx = (float)xx * (31.f / 63.f);
                ry0 = (int)fy; ry1 = min(ry0 + 1, 31); rwy = fy - (float)ry0;
                rx0 = (int)fx; rx1 = min(rx0 + 1, 31); rwx = fx - (float)rx0;
            }
#pragma unroll
            for (int j = 0; j < 4; ++j) {
                float v = acc[mb][nb][j];
                if (bias) v += bias[row + j];
                if (RES_MODE == 1) v += res[base + (size_t)j * P];
                if (RES_MODE == 2) {
                    const float* pl = res + ((size_t)b * Co + row + j) * 1024;
                    const float r0 = pl[ry0 * 32 + rx0] * (1.f - rwx) + pl[ry0 * 32 + rx1] * rwx;
                    const float r1 = pl[ry1 * 32 + rx0] * (1.f - rwx) + pl[ry1 * 32 + rx1] * rwx;
                    v += r0 * (1.f - rwy) + r1 * rwy;
                }
                out[base + (size_t)j * P] = v;
            }
        }
    }
}

// ---------------- fused pair resize 32x32 -> 16x16 for k and v ----------------
__global__ void resize_pair(const float* __restrict__ kv, float* __restrict__ k16,
                            float* __restrict__ v16) {
    const int gb = blockIdx.x;              // 0..4095
    const int which = gb >> 11;             // 0: k, 1: v
    const int idx = (gb & 2047) * 256 + threadIdx.x;
    const int x = idx & 15;
    const int y = (idx >> 4) & 15;
    const int c = (idx >> 8) & 255;
    const int b = idx >> 16;
    const float fy = (float)y * (31.f / 15.f);
    const float fx = (float)x * (31.f / 15.f);
    int y0 = (int)fy; int y1 = min(y0 + 1, 31); const float wy = fy - (float)y0;
    int x0 = (int)fx; int x1 = min(x0 + 1, 31); const float wx = fx - (float)x0;
    const float* pc = kv + (size_t)b * 512 * 1024 + (size_t)(which * 256 + c) * 1024;
    const float r0 = pc[y0 * 32 + x0] * (1.f - wx) + pc[y0 * 32 + x1] * wx;
    const float r1 = pc[y1 * 32 + x0] * (1.f - wx) + pc[y1 * 32 + x1] * wx;
    float* out = which ? v16 : k16;
    out[idx] = r0 * (1.f - wy) + r1 * wy;
}

// ---------------- BN stats, two-phase ----------------
__global__ __launch_bounds__(256, 8)
void bn_stats_part(const float* __restrict__ in, float* __restrict__ part, int C, int HW) {
    const int b = blockIdx.x;
    const int c = blockIdx.y;
    const float* p = in + ((size_t)b * C + c) * HW;
    float s1 = 0.f, s2 = 0.f;
    for (int i = threadIdx.x * 4; i < HW; i += 1024) {
        const float4 v = *reinterpret_cast<const float4*>(p + i);
        s1 += v.x + v.y + v.z + v.w;
        s2 += v.x * v.x + v.y * v.y + v.z * v.z + v.w * v.w;
    }
#pragma unroll
    for (int o = 32; o >= 1; o >>= 1) {
        s1 += __shfl_xor(s1, o);
        s2 += __shfl_xor(s2, o);
    }
    __shared__ float sh1[4], sh2[4];
    if ((threadIdx.x & 63) == 0) { sh1[threadIdx.x >> 6] = s1; sh2[threadIdx.x >> 6] = s2; }
    __syncthreads();
    if (threadIdx.x == 0) {
        part[((size_t)c * gridDim.x + b) * 2 + 0] = sh1[0] + sh1[1] + sh1[2] + sh1[3];
        part[((size_t)c * gridDim.x + b) * 2 + 1] = sh2[0] + sh2[1] + sh2[2] + sh2[3];
    }
}

__global__ void bn_finish(const float* __restrict__ part, const float* __restrict__ g,
                          const float* __restrict__ bt, float* __restrict__ scale,
                          float* __restrict__ shift, int C, int HW, float eps) {
    const int c = blockIdx.x * 256 + threadIdx.x;
    if (c >= C) return;
    float s1 = 0.f, s2 = 0.f;
#pragma unroll
    for (int b = 0; b < NB_; ++b) {
        s1 += part[((size_t)c * NB_ + b) * 2 + 0];
        s2 += part[((size_t)c * NB_ + b) * 2 + 1];
    }
    const float invN = 1.f / (float)(NB_ * HW);
    const float m = s1 * invN;
    const float var = s2 * invN - m * m;
    const float sc = g[c] * rsqrtf(var + eps);
    scale[c] = sc;
    shift[c] = bt[c] - m * sc;
}

// ---------------- fused: LN+split (k16) and packed v^T (independent) ----------------
__global__ void ln_split_packv(const float* __restrict__ k16, const float* __restrict__ g,
                               const float* __restrict__ bt, float* __restrict__ kn,
                               const float* __restrict__ v16, short* __restrict__ Xpv) {
    const int blk = blockIdx.x;
    if (blk < 2048) {
        const int row = blk * 8 + (threadIdx.x >> 5);
        const int d = threadIdx.x & 31;
        const int j = row % 256;
        const int h = (row >> 8) & 7;
        const int b = row >> 11;
        float v = k16[((size_t)b * OUTCH + d * NHEAD + h) * 256 + j];
        float s1 = v, s2 = v * v;
#pragma unroll
        for (int o = 16; o >= 1; o >>= 1) {
            s1 += __shfl_xor(s1, o, 32);
            s2 += __shfl_xor(s2, o, 32);
        }
        const float m = s1 * (1.f / 32.f);
        const float var = s2 * (1.f / 32.f) - m * m;
        v = (v - m) * rsqrtf(var + 1e-6f) * g[h * 32 + d] + bt[h * 32 + d];
        kn[((size_t)(b * NHEAD + h) * 256 + j) * 32 + d] = v;
    } else {
        const int hb = blk - 2048;          // 0..63
        const int h = hb >> 3, b = hb & 7;
        const int tid = threadIdx.x;
#pragma unroll
        for (int cc = 0; cc < 4; ++cc) {
            const int c  = tid * 4 + cc;
            const int d  = c >> 5;
            const int ck = c & 31;
            const int kt = ck >> 2, q = ck & 3;
            const float* vp = v16 + ((size_t)(b * 256 + d * NHEAD + h)) * 256;
            short8v v;
#pragma unroll
            for (int hh = 0; hh < 2; ++hh)
#pragma unroll
                for (int r = 0; r < 4; ++r)
                    v[hh * 4 + r] = f2bf(vp[kt * 32 + hh * 16 + q * 4 + r]);
            *reinterpret_cast<short8v*>(&Xpv[(size_t)h * 65536 + (b * 32 + d) * 256 + kt * 32 + q * 8]) = v;
        }
    }
}

// ---------------- M = k^T v (v read directly from conv-layout v16) ----------------
__global__ void kv_outer(const float* __restrict__ kn, const float* __restrict__ v16,
                         float* __restrict__ M) {
    __shared__ float vs[256][33];
    const int bh = blockIdx.x;
    const int b = bh >> 3, h = bh & 7;
    const float* kp = kn + (size_t)bh * 256 * 32;
    const int tid = threadIdx.y * 32 + threadIdx.x;
    for (int t = tid; t < 256 * 32; t += 1024) {
        const int d = t >> 8, j = t & 255;
        vs[j][d] = v16[((size_t)(b * 256 + d * NHEAD + h)) * 256 + j];
    }
    __syncthreads();
    const int e = threadIdx.x, dd = threadIdx.y;
    float acc = 0.f;
    for (int j = 0; j < 256; ++j) acc += kp[j * 32 + e] * vs[j][dd];
    M[((size_t)bh * 32 + e) * 32 + dd] = acc;
}

// ---------------- attention out: o = (LN(q) @ M + Bv)/32, 2 px/thread, SGPR-M ----------------
// Bv2 layout: [h][qb][b*32+d]
__global__ __launch_bounds__(256, 2)
void attn_out(const float* __restrict__ q, const float* __restrict__ gq,
              const float* __restrict__ bq, const float* __restrict__ M,
              const float* __restrict__ Bv, float* __restrict__ o) {
    const int gid = blockIdx.x * 256 + threadIdx.x;
    const int ip = (gid & 2047) * 2;
    const int h  = (gid >> 11) & 7;
    const int b  = gid >> 14;

    const float* Mp = M + ((size_t)(b * NHEAD + h) << 10);
    {
        uint64_t a = (uint64_t)Mp;
        uint32_t lo = __builtin_amdgcn_readfirstlane((uint32_t)a);
        uint32_t hi = __builtin_amdgcn_readfirstlane((uint32_t)(a >> 32));
        Mp = (const float*)((((uint64_t)hi) << 32) | lo);
    }

    const float* qp = q + (size_t)b * OUTCH * 4096 + h * 4096 + ip;
    float q0[32], q1[32];
    float a1 = 0.f, a2 = 0.f, b1 = 0.f, b2 = 0.f;
#pragma unroll
    for (int d = 0; d < 32; ++d) {
        const float2 v = *reinterpret_cast<const float2*>(qp + (size_t)d * NHEAD * 4096);
        q0[d] = v.x; q1[d] = v.y;
        a1 += v.x; a2 += v.x * v.x;
        b1 += v.y; b2 += v.y * v.y;
    }
    {
        const float m0 = a1 * (1.f / 32.f);
        const float r0 = rsqrtf(a2 * (1.f / 32.f) - m0 * m0 + 1e-6f);
        const float m1 = b1 * (1.f / 32.f);
        const float r1 = rsqrtf(b2 * (1.f / 32.f) - m1 * m1 + 1e-6f);
#pragma unroll
        for (int d = 0; d < 32; ++d) {
            const float gg = gq[h * 32 + d], bb = bq[h * 32 + d];
            q0[d] = (q0[d] - m0) * r0 * gg + bb;
            q1[d] = (q1[d] - m1) * r1 * gg + bb;
        }
    }

    const int y = ip >> 6, x = ip & 63;
    const int qb0 = (y >> 2) * 16 + (x >> 2);
    const int qb1 = (y >> 2) * 16 + ((x + 1) >> 2);
    const float* Bp0 = Bv + ((size_t)h * 256 + qb0) * 256 + b * 32;
    const float* Bp1 = Bv + ((size_t)h * 256 + qb1) * 256 + b * 32;
    float acc0[32], acc1[32];
#pragma unroll
    for (int t = 0; t < 8; ++t) {
        const float4 v0 = *reinterpret_cast<const float4*>(Bp0 + t * 4);
        const float4 v1 = *reinterpret_cast<const float4*>(Bp1 + t * 4);
        acc0[t * 4 + 0] = v0.x; acc0[t * 4 + 1] = v0.y; acc0[t * 4 + 2] = v0.z; acc0[t * 4 + 3] = v0.w;
        acc1[t * 4 + 0] = v1.x; acc1[t * 4 + 1] = v1.y; acc1[t * 4 + 2] = v1.z; acc1[t * 4 + 3] = v1.w;
    }

    for (int e = 0; e < 32; ++e) {
        const float qe0 = q0[e], qe1 = q1[e];
#pragma unroll
        for (int d = 0; d < 32; ++d) {
            const float m = Mp[e * 32 + d];
            acc0[d] += qe0 * m;
            acc1[d] += qe1 * m;
        }
    }

    float* op = o + (size_t)b * OUTCH * 4096 + h * 4096 + ip;
#pragma unroll
    for (int d = 0; d < 32; ++d) {
        float2 v;
        v.x = acc0[d] * (1.f / 32.f);
        v.y = acc1[d] * (1.f / 32.f);
        *reinterpret_cast<float2*>(op + (size_t)d * NHEAD * 4096) = v;
    }
}

extern "C" void kernel_launch(void* const* d_in, const int* in_sizes, int n_in,
                              void* d_out, int out_size, void* d_ws, size_t ws_size,
                              hipStream_t stream) {
    const float* x1        = (const float*)d_in[0];
    const float* x2        = (const float*)d_in[1];
    const float* conv_ch_w = (const float*)d_in[2];
    const float* conv_ch_b = (const float*)d_in[3];
    const float* norm_l_g  = (const float*)d_in[4];
    const float* norm_l_b  = (const float*)d_in[5];
    const float* norm_h_g  = (const float*)d_in[6];
    const float* norm_h_b  = (const float*)d_in[7];
    const float* to_kv_dw  = (const float*)d_in[8];
    const float* to_kv_pw  = (const float*)d_in[9];
    const float* to_q_dw   = (const float*)d_in[10];
    const float* to_q_pw   = (const float*)d_in[11];
    const float* to_out_dw = (const float*)d_in[12];
    const float* to_out_pw = (const float*)d_in[13];
    const float* rel_table = (const float*)d_in[14];
    const float* normq_g   = (const float*)d_in[15];
    const float* normq_b   = (const float*)d_in[16];
    const float* normk_g   = (const float*)d_in[17];
    const float* normk_b   = (const float*)d_in[18];
    const float* norm2_g   = (const float*)d_in[19];
    const float* norm2_b   = (const float*)d_in[20];
    const float* mlp_w     = (const float*)d_in[21];
    float* Dout = (float*)d_out;

    float* ws = (float*)d_ws;
    const size_t NBIG = (size_t)NB_ * OUTCH * 4096;  // 8388608 floats (32 MB)
    float* X1C = ws;               // x1c kept alive: [8][256][1024] = 8 MB
    float* A   = ws + NBIG;
    float* Bb  = ws + 2 * NBIG;
    float* sm  = ws + 3 * NBIG;
    float* scale1 = sm;            float* shift1 = sm + 512;
    float* scale2 = sm + 1024;     float* shift2 = sm + 1280;
    float* scale3 = sm + 1536;     float* shift3 = sm + 1792;
    float* k16 = sm + 2048;
    float* v16 = k16 + 524288;
    float* kn  = v16 + 524288;
    float* vh  = kn  + 524288;     // (unused slot retained for layout stability)
    float* Mm  = vh  + 524288;
    float* Bv  = Mm  + 65536;      // Bv2: [h][qb][b*32+d], 524288 floats
    short* Wq  = (short*)(Bv + 524288);
    short* Wo  = Wq + 65536;
    short* Wm  = Wo + 65536;
    short* Wc  = Wm + 65536;       // conv_ch_w packed: 256x512
    short* Wkv = Wc + 131072;      // to_kv_pw packed: 512x512
    float* bnpart = (float*)(Wkv + 262144);  // 8192 floats max

    short* Xp1 = (short*)Bb;             // x1 packed: 8 MB
    short* Xp2 = (short*)Bb + 4194304;   // kv_dw packed: 8 MB
    short* Xp  = (short*)Bb;             // big packed X (16 MB), steps 8+
    short* Bmp = (short*)Bb + 8388608;   // bias matrices: 1 MB
    short* Xpv = Bmp + 524288;           // packed v^T: 1 MB
    float* kv  = A;                      // 16 MB fp32 [8,512,1024]

    // 0. fused setup: pack 5 weights + bias matrix
    pack_all<<<4352, 256, 0, stream>>>(to_q_pw, to_out_pw, mlp_w, conv_ch_w, to_kv_pw, rel_table,
                                       Wq, Wo, Wm, Wc, Wkv, Bmp);

    // 1. x1 -> packed bf16; x1c = mfma(x1p, Wc) + bias -> X1C (kept alive)
    pack_tile<0><<<dim3(4, 16, 8), 256, 0, stream>>>(x1, nullptr, nullptr, Xp1, 512, 1024);
    mfma_pw<0, 0><<<dim3(16, 2, 8), 256, 0, stream>>>(Xp1, Wc, conv_ch_b, nullptr, X1C, 512, 256, 1024);
    // 3. BN stats x1 (two-phase)
    bn_stats_part<<<dim3(8, 512), 256, 0, stream>>>(x1, bnpart, 512, 1024);
    bn_finish<<<2, 256, 0, stream>>>(bnpart, norm_l_g, norm_l_b, scale1, shift1, 512, 1024, 1e-5f);
    // 4. kv_dw = dw3(BN(x1)) -> Xp2 (packed bf16)
    dw3_direct<32><<<dim3(4, 16, 8), 256, 0, stream>>>(x1, scale1, shift1, to_kv_dw, Xp2, 512, 32);
    // 5. kv = mfma(Xp2, Wkv) -> A
    mfma_pw<0, 0><<<dim3(16, 4, 8), 256, 0, stream>>>(Xp2, Wkv, nullptr, nullptr, kv, 512, 512, 1024);
    // 6. k16, v16 (fused pair)
    resize_pair<<<4096, 256, 0, stream>>>(kv, k16, v16);
    // 7. BN stats x2 (two-phase)
    bn_stats_part<<<dim3(8, 256), 256, 0, stream>>>(x2, bnpart, 256, 4096);
    bn_finish<<<1, 256, 0, stream>>>(bnpart, norm_h_g, norm_h_b, scale2, shift2, 256, 4096, 1e-5f);
    // 8. q_dw = dw3(BN(x2)) -> Xp (packed bf16)
    dw3_direct<64><<<dim3(16, 8, 8), 256, 0, stream>>>(x2, scale2, shift2, to_q_dw, Xp, 256, 64);
    // 9. q = mfma(Xp, Wq) -> A
    mfma_pw<0, 0><<<dim3(64, 2, 8), 256, 0, stream>>>(Xp, Wq, nullptr, nullptr, A, 256, 256, 4096);
    // 10. kn = LN(split(k16)) + Xpv = packed v^T (fused)
    ln_split_packv<<<2112, 256, 0, stream>>>(k16, normk_g, normk_b, kn, v16, Xpv);
    // 11. M = k^T v (v16 read directly)
    kv_outer<<<64, dim3(32, 32), 0, stream>>>(kn, v16, Mm);
    // 12. Bv2[h][qb][b*32+d] = bias_h @ V_h  (batched MFMA GEMM)
    mfma_pw<0, 1><<<dim3(4, 2, 8), 256, 0, stream>>>(Xpv, Bmp, nullptr, nullptr, Bv, 256, 256, 256);
    // 13. o = (LN(q) @ M + Bv)/32, in-place on A
    attn_out<<<512, 256, 0, stream>>>(A, normq_g, normq_b, Mm, Bv, A);
    // 14. out_dw = dw3(o) -> Xp (packed bf16)
    dw3_direct<64><<<dim3(16, 8, 8), 256, 0, stream>>>(A, nullptr, nullptr, to_out_dw, Xp, 256, 64);
    // 15. o2 = mfma(Xp, Wo) + bilinear(X1C) -> A  (res2; residue fused in epilogue)
    mfma_pw<2, 0><<<dim3(64, 2, 8), 256, 0, stream>>>(Xp, Wo, nullptr, X1C, A, 256, 256, 4096);
    // 16. BN stats o2 (two-phase)
    bn_stats_part<<<dim3(8, 256), 256, 0, stream>>>(A, bnpart, 256, 4096);
    bn_finish<<<1, 256, 0, stream>>>(bnpart, norm2_g, norm2_b, scale3, shift3, 256, 4096, 1e-5f);
    // 17. r = relu(BN(o2)) -> Xp (packed bf16)
    pack_tile<1><<<dim3(16, 8, 8), 256, 0, stream>>>(A, scale3, shift3, Xp, 256, 4096);
    // 18. out = mfma(Xp, Wm) + res2(A) -> d_out
    mfma_pw<1, 0><<<dim3(64, 2, 8), 256, 0, stream>>>(Xp, Wm, nullptr, A, Dout, 256, 256, 4096);
}